// Round 1
// baseline (3579.347 us; speedup 1.0000x reference)
//
#include <hip/hip_runtime.h>
#include <stdint.h>

// ---------------- problem constants ----------------
#define NLAYER 13
#define DMODEL 512
#define SEQ    65
#define BATCH  128
#define MROWS  (BATCH*SEQ)   // 8320 = 65 * 128 exactly
#define NHEAD  8
#define DFFH   1920          // half of 2*DFF

typedef __bf16 bf16x8 __attribute__((ext_vector_type(8)));
typedef float  f32x4  __attribute__((ext_vector_type(4)));

__device__ __forceinline__ float bf2f(unsigned short u) {
    union { unsigned int i; float f; } c; c.i = ((unsigned int)u) << 16; return c.f;
}
__device__ __forceinline__ unsigned short f2bf(float f) {
    union { float f; unsigned int i; } c; c.f = f;
    unsigned int u = c.i;
    u += 0x7fffu + ((u >> 16) & 1u);   // RNE
    return (unsigned short)(u >> 16);
}
__device__ __forceinline__ float gelu_exact(float x) {
    return 0.5f * x * (1.0f + erff(x * 0.70710678118654752f));
}

// ---------------- weight convert + transpose to bf16 ----------------
// src: (L, R, C) fp32 ; dst: per-layer (rows..) bf16 at dst + l*dstLS + (rowOff+c)*R + r
// pads dst rows [C, Cpad) with zeros.
__global__ __launch_bounds__(256) void transpose_f32_bf16(
    const float* __restrict__ src, unsigned short* __restrict__ dst,
    int R, int C, int Cpad, long srcLS, long dstLS, int rowOff)
{
    __shared__ float tile[32][33];
    int l  = blockIdx.z;
    int c0 = blockIdx.x * 32, r0 = blockIdx.y * 32;
    const float* s = src + (long)l * srcLS;
    unsigned short* d = dst + (long)l * dstLS;
    int tx = threadIdx.x, ty = threadIdx.y;
#pragma unroll
    for (int k = 0; k < 4; k++) {
        int r = r0 + ty + 8*k, c = c0 + tx;
        float v = (r < R && c < C) ? s[(long)r * C + c] : 0.0f;
        tile[ty + 8*k][tx] = v;
    }
    __syncthreads();
#pragma unroll
    for (int k = 0; k < 4; k++) {
        int c = c0 + ty + 8*k, r = r0 + tx;
        if (c < Cpad && r < R)
            d[(long)(rowOff + c) * R + r] = f2bf(tile[tx][ty + 8*k]);
    }
}

// ---------------- stack bq|bk|bv -> (L,1536) ----------------
__global__ __launch_bounds__(256) void stack_bias_kernel(
    const float* __restrict__ bq, const float* __restrict__ bk,
    const float* __restrict__ bv, float* __restrict__ bqkv)
{
    int idx = blockIdx.x * 256 + threadIdx.x;
    if (idx >= NLAYER * 1536) return;
    int l = idx / 1536, r = idx - l * 1536;
    float v;
    if (r < 512)       v = bq[l*512 + r];
    else if (r < 1024) v = bk[l*512 + r - 512];
    else               v = bv[l*512 + r - 1024];
    bqkv[idx] = v;
}

// ---------------- embedding: conv1x1 + positional sums + cls ----------------
// grid (9, B): sg<8 -> 8 squares each ; sg==8 -> cls row
__global__ __launch_bounds__(256) void embed_kernel(
    const float* __restrict__ x, const float* __restrict__ conv_w,
    const float* __restrict__ conv_b, const float* __restrict__ cls_tok,
    const float* __restrict__ abs_pos, const float* __restrict__ file_emb,
    const float* __restrict__ rank_emb, const float* __restrict__ diag_emb,
    const float* __restrict__ adiag_emb, float* __restrict__ h)
{
    int b = blockIdx.y, sg = blockIdx.x, t = threadIdx.x;
    if (sg == 8) {
        for (int d = t; d < 512; d += 256)
            h[(long)b * SEQ * 512 + d] = cls_tok[d];
        return;
    }
    __shared__ float xs[112][8];
    for (int idx = t; idx < 112*8; idx += 256) {
        int c = idx >> 3, j = idx & 7;
        xs[c][j] = x[((long)b*112 + c)*64 + sg*8 + j];
    }
    __syncthreads();
    int d0 = t, d1 = t + 256;
    float acc0[8] = {}, acc1[8] = {};
    for (int c = 0; c < 112; c++) {
        float w0 = conv_w[c*512 + d0], w1 = conv_w[c*512 + d1];
#pragma unroll
        for (int j = 0; j < 8; j++) { acc0[j] += xs[c][j]*w0; acc1[j] += xs[c][j]*w1; }
    }
#pragma unroll
    for (int j = 0; j < 8; j++) {
        int sq = sg*8 + j, r = sq >> 3, f = sq & 7;
        long row = ((long)b * SEQ + 1 + sq) * 512;
        h[row + d0] = acc0[j] + conv_b[d0] + abs_pos[sq*512+d0] + file_emb[f*512+d0]
                    + rank_emb[r*512+d0] + diag_emb[(r+f)*512+d0] + adiag_emb[(r-f+7)*512+d0];
        h[row + d1] = acc1[j] + conv_b[d1] + abs_pos[sq*512+d1] + file_emb[f*512+d1]
                    + rank_emb[r*512+d1] + diag_emb[(r+f)*512+d1] + adiag_emb[(r-f+7)*512+d1];
    }
}

// ---------------- LayerNorm fp32 -> bf16 (wave per row) ----------------
__global__ __launch_bounds__(256) void ln_kernel(
    const float* __restrict__ hx, const float* __restrict__ g,
    const float* __restrict__ bb, unsigned short* __restrict__ o)
{
    int row  = blockIdx.x * 4 + (threadIdx.x >> 6);
    int lane = threadIdx.x & 63;
    const float4* xr = (const float4*)(hx + (long)row * 512);
    float4 v0 = xr[lane], v1 = xr[lane + 64];
    float s  = v0.x+v0.y+v0.z+v0.w + v1.x+v1.y+v1.z+v1.w;
    float s2 = v0.x*v0.x+v0.y*v0.y+v0.z*v0.z+v0.w*v0.w
             + v1.x*v1.x+v1.y*v1.y+v1.z*v1.z+v1.w*v1.w;
    for (int off = 32; off; off >>= 1) { s += __shfl_xor(s, off); s2 += __shfl_xor(s2, off); }
    float mean = s * (1.0f/512.0f);
    float var  = s2 * (1.0f/512.0f) - mean*mean;
    float rs   = rsqrtf(var + 1e-5f);
    const float4* gr = (const float4*)g; const float4* br = (const float4*)bb;
    float4 g0 = gr[lane], g1 = gr[lane+64], b0 = br[lane], b1 = br[lane+64];
    ushort4 o0, o1;
    o0.x = f2bf((v0.x-mean)*rs*g0.x + b0.x);
    o0.y = f2bf((v0.y-mean)*rs*g0.y + b0.y);
    o0.z = f2bf((v0.z-mean)*rs*g0.z + b0.z);
    o0.w = f2bf((v0.w-mean)*rs*g0.w + b0.w);
    o1.x = f2bf((v1.x-mean)*rs*g1.x + b1.x);
    o1.y = f2bf((v1.y-mean)*rs*g1.y + b1.y);
    o1.z = f2bf((v1.z-mean)*rs*g1.z + b1.z);
    o1.w = f2bf((v1.w-mean)*rs*g1.w + b1.w);
    ushort4* orow = (ushort4*)(o + (long)row * 512);
    orow[lane] = o0; orow[lane + 64] = o1;
}

// ---------------- MFMA GEMM: C[M,N] = A[M,K](bf16) * Bt[N,K]^T(bf16) + epi ----------------
// tile 128x128, BK=32, 4 waves (each 32 rows x 128 cols), 16x16x32 MFMA
// MODE 0: bias, store bf16 (ldo)     MODE 1: bias + fp32 residual, store fp32 (ldo)
// MODE 2: GLU pair (tile = u1[n0..n0+64) | u2[..]), store bf16 gelu(u1)*u2, out (M,1920)
// MODE 3: policy masked store: cols<72, rows with s>0, out fp32 (B,4608)
template<int MODE>
__global__ __launch_bounds__(256) void gemm128(
    const unsigned short* __restrict__ A, const unsigned short* __restrict__ Bt,
    const float* __restrict__ bias, const float* __restrict__ res,
    void* __restrict__ out, int K, int ldo)
{
    __shared__ __attribute__((aligned(16))) unsigned short As[128*32];
    __shared__ __attribute__((aligned(16))) unsigned short Bs[128*32];
    int m0 = blockIdx.x * 128;
    int bn = blockIdx.y;
    int tid = threadIdx.x;
    int lane = tid & 63, w = tid >> 6;
    int quad = lane >> 4, col = lane & 15;

    int srow = tid >> 2;          // 0..63
    int sc8  = (tid & 3) * 8;     // k element offset (8 bf16 = 16B)

    int br0, br1;
    if (MODE == 2) {
        br0 = bn*64 + srow;                 // u1 rows
        br1 = 1920 + bn*64 + srow;          // u2 rows
    } else {
        br0 = bn*128 + srow;
        br1 = bn*128 + srow + 64;
    }
    const unsigned short* Arow0 = A + (long)(m0 + srow) * K;
    const unsigned short* Arow1 = A + (long)(m0 + srow + 64) * K;
    const unsigned short* Brow0 = Bt + (long)br0 * K;
    const unsigned short* Brow1 = Bt + (long)br1 * K;

    f32x4 acc[2][8] = {};

    int4 ca0 = *(const int4*)(Arow0 + sc8);
    int4 ca1 = *(const int4*)(Arow1 + sc8);
    int4 cb0 = *(const int4*)(Brow0 + sc8);
    int4 cb1 = *(const int4*)(Brow1 + sc8);

    for (int k0 = 0; k0 < K; k0 += 32) {
        __syncthreads();   // prior iteration's frag reads done
        *(int4*)(&As[srow*32 + sc8])        = ca0;
        *(int4*)(&As[(srow+64)*32 + sc8])   = ca1;
        *(int4*)(&Bs[srow*32 + sc8])        = cb0;
        *(int4*)(&Bs[(srow+64)*32 + sc8])   = cb1;
        __syncthreads();
        int kn = k0 + 32;
        if (kn < K) {   // prefetch next tile while computing
            ca0 = *(const int4*)(Arow0 + kn + sc8);
            ca1 = *(const int4*)(Arow1 + kn + sc8);
            cb0 = *(const int4*)(Brow0 + kn + sc8);
            cb1 = *(const int4*)(Brow1 + kn + sc8);
        }
        bf16x8 af[2], bfr[8];
#pragma unroll
        for (int i = 0; i < 2; i++)
            af[i] = *(const bf16x8*)(&As[(w*32 + i*16 + col)*32 + quad*8]);
#pragma unroll
        for (int t = 0; t < 8; t++)
            bfr[t] = *(const bf16x8*)(&Bs[(t*16 + col)*32 + quad*8]);
#pragma unroll
        for (int i = 0; i < 2; i++)
#pragma unroll
            for (int t = 0; t < 8; t++)
                acc[i][t] = __builtin_amdgcn_mfma_f32_16x16x32_bf16(af[i], bfr[t], acc[i][t], 0, 0, 0);
    }

    // ---- epilogue ----  C/D layout: col = lane&15, row = quad*4 + reg  [m89/m91]
    if (MODE == 2) {
        unsigned short* O = (unsigned short*)out;
        int gn0 = bn * 64;
#pragma unroll
        for (int i = 0; i < 2; i++)
#pragma unroll
        for (int t = 0; t < 4; t++) {
            int c = t*16 + col;
            float b1v = bias[gn0 + c];
            float b2v = bias[1920 + gn0 + c];
#pragma unroll
            for (int r = 0; r < 4; r++) {
                int m = m0 + w*32 + i*16 + quad*4 + r;
                float u1 = acc[i][t][r]   + b1v;
                float u2 = acc[i][t+4][r] + b2v;
                O[(long)m * DFFH + gn0 + c] = f2bf(gelu_exact(u1) * u2);
            }
        }
        return;
    }
    int n0 = bn * 128;
#pragma unroll
    for (int i = 0; i < 2; i++)
#pragma unroll
    for (int t = 0; t < 8; t++) {
        int cg = n0 + t*16 + col;
        float bv = (MODE == 3) ? (cg < 72 ? bias[cg] : 0.0f) : bias[cg];
#pragma unroll
        for (int r = 0; r < 4; r++) {
            int m = m0 + w*32 + i*16 + quad*4 + r;
            float v = acc[i][t][r] + bv;
            if (MODE == 0) {
                ((unsigned short*)out)[(long)m * ldo + cg] = f2bf(v);
            } else if (MODE == 1) {
                ((float*)out)[(long)m * ldo + cg] = res[(long)m * ldo + cg] + v;
            } else { // MODE 3 policy
                if (cg < 72) {
                    int b2 = m / 65, s = m - b2 * 65;
                    if (s > 0)
                        ((float*)out)[(long)b2 * 4608 + (s - 1) * 72 + cg] = v;
                }
            }
        }
    }
}

// ---------------- attention: one block per (head, batch) ----------------
__global__ __launch_bounds__(256) void attn_kernel(
    const unsigned short* __restrict__ qkv,   // (M,1536) bf16: q|k|v
    const float* __restrict__ rel_bias,       // (13,15,15,8)
    unsigned short* __restrict__ ctx,         // (M,512) bf16
    int layer)
{
    int hh = blockIdx.x, b = blockIdx.y, t = threadIdx.x;
    __shared__ float qs[65*64];
    __shared__ unsigned short ks[65*64];
    __shared__ unsigned short vs[65*64];
    __shared__ float sc[65*66];

    for (int idx = t; idx < 65*64; idx += 256) {
        int s = idx >> 6, ii = idx & 63;
        long base = ((long)(b * SEQ + s)) * 1536 + hh * 64 + ii;
        qs[idx] = bf2f(qkv[base]) * 0.125f;   // 1/sqrt(64)
        ks[idx] = qkv[base + 512];
        vs[idx] = qkv[base + 1024];
    }
    __syncthreads();

    // scores: 17x17 tiles of 4x4 (last tile clamped to start 61, stores only idx 64)
    for (int tt = t; tt < 17*17; tt += 256) {
        int ti = tt / 17, tj = tt - ti*17;
        int qi0 = (ti < 16) ? ti*4 : 61;
        int kj0 = (tj < 16) ? tj*4 : 61;
        float a[4][4] = {};
        for (int kk = 0; kk < 64; kk++) {
            float qv[4], kv[4];
#pragma unroll
            for (int u = 0; u < 4; u++) { qv[u] = qs[(qi0+u)*64 + kk]; kv[u] = bf2f(ks[(kj0+u)*64 + kk]); }
#pragma unroll
            for (int u = 0; u < 4; u++)
#pragma unroll
                for (int v2 = 0; v2 < 4; v2++) a[u][v2] += qv[u] * kv[v2];
        }
#pragma unroll
        for (int u = 0; u < 4; u++)
#pragma unroll
        for (int v2 = 0; v2 < 4; v2++) {
            int qi = qi0 + u, kj = kj0 + v2;
            bool keep = (ti < 16 || qi == 64) && (tj < 16 || kj == 64);
            if (!keep) continue;
            float v = a[u][v2];
            if (qi >= 1 && kj >= 1) {
                int i2 = qi - 1, j2 = kj - 1;
                int dr = (i2 >> 3) - (j2 >> 3) + 7;
                int df = (i2 & 7) - (j2 & 7) + 7;
                v += rel_bias[(((long)layer * 15 + dr) * 15 + df) * 8 + hh];
            }
            sc[qi*66 + kj] = v;
        }
    }
    __syncthreads();

    // softmax per row (wave per row)
    int wv = t >> 6, lane = t & 63;
    for (int r = wv; r < 65; r += 4) {
        float x0 = sc[r*66 + lane];
        float x1 = (lane == 0) ? sc[r*66 + 64] : -1e30f;
        float mx = fmaxf(x0, x1);
        for (int off = 32; off; off >>= 1) mx = fmaxf(mx, __shfl_xor(mx, off));
        float e0 = __expf(x0 - mx);
        float e1 = (lane == 0) ? __expf(x1 - mx) : 0.0f;
        float sm = e0 + e1;
        for (int off = 32; off; off >>= 1) sm += __shfl_xor(sm, off);
        float inv = 1.0f / sm;
        sc[r*66 + lane] = e0 * inv;
        if (lane == 0) sc[r*66 + 64] = e1 * inv;
    }
    __syncthreads();

    // ctx = P @ V : 17x16 tiles of 4x4
    for (int tt = t; tt < 17*16; tt += 256) {
        int ti = tt / 16, i0 = (tt - ti*16) * 4;
        int qi0 = (ti < 16) ? ti*4 : 61;
        float a[4][4] = {};
        for (int kj = 0; kj <= 64; kj++) {
            float pv[4], vvv[4];
#pragma unroll
            for (int u = 0; u < 4; u++) { pv[u] = sc[(qi0+u)*66 + kj]; vvv[u] = bf2f(vs[kj*64 + i0 + u]); }
#pragma unroll
            for (int u = 0; u < 4; u++)
#pragma unroll
                for (int v2 = 0; v2 < 4; v2++) a[u][v2] += pv[u] * vvv[v2];
        }
#pragma unroll
        for (int u = 0; u < 4; u++) {
            int qi = qi0 + u;
            bool keep = (ti < 16 || qi == 64);
            if (!keep) continue;
#pragma unroll
            for (int v2 = 0; v2 < 4; v2++)
                ctx[((long)(b * SEQ + qi)) * 512 + hh*64 + i0 + v2] = f2bf(a[u][v2]);
        }
    }
}

// ---------------- value head (block per batch row) ----------------
__global__ __launch_bounds__(256) void value_head_kernel(
    const unsigned short* __restrict__ hn,
    const float* __restrict__ vw1, const float* __restrict__ vb1,
    const float* __restrict__ vw2, const float* __restrict__ vb2,
    const float* __restrict__ vw3, const float* __restrict__ vb3,
    float* __restrict__ outv)
{
    int b = blockIdx.x, t = threadIdx.x;
    __shared__ float cls[512], v1[256], v2[128];
    for (int d = t; d < 512; d += 256) cls[d] = bf2f(hn[(long)b * SEQ * 512 + d]);
    __syncthreads();
    {
        float a = vb1[t];
        for (int c = 0; c < 512; c++) a += cls[c] * vw1[c*256 + t];
        v1[t] = gelu_exact(a);
    }
    __syncthreads();
    if (t < 128) {
        float a = vb2[t];
        for (int c = 0; c < 256; c++) a += v1[c] * vw2[c*128 + t];
        v2[t] = gelu_exact(a);
    }
    __syncthreads();
    if (t < 3) {
        float a = vb3[t];
        for (int c = 0; c < 128; c++) a += v2[c] * vw3[c*3 + t];
        outv[b*3 + t] = a;
    }
}

// ---------------- host orchestration ----------------
extern "C" void kernel_launch(void* const* d_in, const int* in_sizes, int n_in,
                              void* d_out, int out_size, void* d_ws, size_t ws_size,
                              hipStream_t stream)
{
    (void)in_sizes; (void)n_in; (void)out_size; (void)ws_size;
    const float* x        = (const float*)d_in[0];
    const float* conv_w   = (const float*)d_in[1];
    const float* conv_b   = (const float*)d_in[2];
    const float* cls_tok  = (const float*)d_in[3];
    const float* abs_pos  = (const float*)d_in[4];
    const float* file_emb = (const float*)d_in[5];
    const float* rank_emb = (const float*)d_in[6];
    const float* diag_emb = (const float*)d_in[7];
    const float* adiag    = (const float*)d_in[8];
    const float* ln1_g    = (const float*)d_in[9];
    const float* ln1_b    = (const float*)d_in[10];
    const float* wq       = (const float*)d_in[11];
    const float* bq       = (const float*)d_in[12];
    const float* wk       = (const float*)d_in[13];
    const float* bk       = (const float*)d_in[14];
    const float* wv       = (const float*)d_in[15];
    const float* bv       = (const float*)d_in[16];
    const float* wo       = (const float*)d_in[17];
    const float* bo       = (const float*)d_in[18];
    const float* rel_bias = (const float*)d_in[19];
    const float* ln2_g    = (const float*)d_in[20];
    const float* ln2_b    = (const float*)d_in[21];
    const float* w_ff1    = (const float*)d_in[22];
    const float* b_ff1    = (const float*)d_in[23];
    const float* w_ff2    = (const float*)d_in[24];
    const float* b_ff2    = (const float*)d_in[25];
    const float* out_g    = (const float*)d_in[26];
    const float* out_b    = (const float*)d_in[27];
    const float* vw1      = (const float*)d_in[28];
    const float* vb1      = (const float*)d_in[29];
    const float* vw2      = (const float*)d_in[30];
    const float* vb2      = (const float*)d_in[31];
    const float* vw3      = (const float*)d_in[32];
    const float* vb3      = (const float*)d_in[33];
    const float* pw       = (const float*)d_in[34];
    const float* pb       = (const float*)d_in[35];

    // workspace layout (~196 MB)
    char* p = (char*)d_ws;
    auto alloc = [&](size_t bytes) { void* r = (void*)p; p += (bytes + 255) & ~(size_t)255; return r; };
    unsigned short* qkvT = (unsigned short*)alloc((size_t)NLAYER*1536*512*2);
    unsigned short* woT  = (unsigned short*)alloc((size_t)NLAYER*512*512*2);
    unsigned short* w1T  = (unsigned short*)alloc((size_t)NLAYER*3840*512*2);
    unsigned short* w2T  = (unsigned short*)alloc((size_t)NLAYER*512*1920*2);
    unsigned short* pwT  = (unsigned short*)alloc((size_t)128*512*2);
    float*          bqkv = (float*)alloc((size_t)NLAYER*1536*4);
    float*          h    = (float*)alloc((size_t)MROWS*512*4);
    unsigned short* nbf  = (unsigned short*)alloc((size_t)MROWS*512*2);
    unsigned short* qkvb = (unsigned short*)alloc((size_t)MROWS*1536*2);
    unsigned short* ctxb = (unsigned short*)alloc((size_t)MROWS*512*2);
    unsigned short* gbuf = (unsigned short*)alloc((size_t)MROWS*1920*2);

    dim3 tb(32, 8);
    // weight transposes -> bf16 B^T
    transpose_f32_bf16<<<dim3(16,16,NLAYER), tb, 0, stream>>>(wq, qkvT, 512, 512, 512, 512L*512, 1536L*512, 0);
    transpose_f32_bf16<<<dim3(16,16,NLAYER), tb, 0, stream>>>(wk, qkvT, 512, 512, 512, 512L*512, 1536L*512, 512);
    transpose_f32_bf16<<<dim3(16,16,NLAYER), tb, 0, stream>>>(wv, qkvT, 512, 512, 512, 512L*512, 1536L*512, 1024);
    transpose_f32_bf16<<<dim3(16,16,NLAYER), tb, 0, stream>>>(wo, woT, 512, 512, 512, 512L*512, 512L*512, 0);
    transpose_f32_bf16<<<dim3(120,16,NLAYER), tb, 0, stream>>>(w_ff1, w1T, 512, 3840, 3840, 512L*3840, 3840L*512, 0);
    transpose_f32_bf16<<<dim3(16,60,NLAYER), tb, 0, stream>>>(w_ff2, w2T, 1920, 512, 512, 1920L*512, 512L*1920, 0);
    transpose_f32_bf16<<<dim3(4,16,1), tb, 0, stream>>>(pw, pwT, 512, 72, 128, 0, 0, 0);
    stack_bias_kernel<<<(NLAYER*1536 + 255)/256, 256, 0, stream>>>(bq, bk, bv, bqkv);

    embed_kernel<<<dim3(9, BATCH), 256, 0, stream>>>(x, conv_w, conv_b, cls_tok, abs_pos,
                                                     file_emb, rank_emb, diag_emb, adiag, h);

    for (int l = 0; l < NLAYER; l++) {
        ln_kernel<<<MROWS/4, 256, 0, stream>>>(h, ln1_g + l*512, ln1_b + l*512, nbf);
        gemm128<0><<<dim3(65,12), 256, 0, stream>>>(nbf, qkvT + (size_t)l*1536*512,
                                                    bqkv + l*1536, nullptr, qkvb, 512, 1536);
        attn_kernel<<<dim3(NHEAD, BATCH), 256, 0, stream>>>(qkvb, rel_bias, ctxb, l);
        gemm128<1><<<dim3(65,4), 256, 0, stream>>>(ctxb, woT + (size_t)l*512*512,
                                                   bo + l*512, h, h, 512, 512);
        ln_kernel<<<MROWS/4, 256, 0, stream>>>(h, ln2_g + l*512, ln2_b + l*512, nbf);
        gemm128<2><<<dim3(65,30), 256, 0, stream>>>(nbf, w1T + (size_t)l*3840*512,
                                                    b_ff1 + l*3840, nullptr, gbuf, 512, 0);
        gemm128<1><<<dim3(65,4), 256, 0, stream>>>(gbuf, w2T + (size_t)l*512*1920,
                                                   b_ff2 + l*512, h, h, 1920, 512);
    }

    ln_kernel<<<MROWS/4, 256, 0, stream>>>(h, out_g, out_b, nbf);
    gemm128<3><<<dim3(65,1), 256, 0, stream>>>(nbf, pwT, pb, nullptr, (float*)d_out, 512, 0);
    value_head_kernel<<<BATCH, 256, 0, stream>>>(nbf, vw1, vb1, vw2, vb2, vw3, vb3,
                                                 (float*)d_out + (size_t)BATCH*4608);
}

// Round 2
// 3272.626 us; speedup vs baseline: 1.0937x; 1.0937x over previous
//
#include <hip/hip_runtime.h>
#include <stdint.h>

// ---------------- problem constants ----------------
#define NLAYER 13
#define DMODEL 512
#define SEQ    65
#define BATCH  128
#define MROWS  (BATCH*SEQ)   // 8320 = 65 * 128 exactly
#define NHEAD  8
#define DFFH   1920          // half of 2*DFF

typedef __bf16 bf16x8 __attribute__((ext_vector_type(8)));
typedef float  f32x4  __attribute__((ext_vector_type(4)));

__device__ __forceinline__ float bf2f(unsigned short u) {
    union { unsigned int i; float f; } c; c.i = ((unsigned int)u) << 16; return c.f;
}
__device__ __forceinline__ unsigned short f2bf(float f) {
    union { float f; unsigned int i; } c; c.f = f;
    unsigned int u = c.i;
    u += 0x7fffu + ((u >> 16) & 1u);   // RNE
    return (unsigned short)(u >> 16);
}
__device__ __forceinline__ float gelu_exact(float x) {
    return 0.5f * x * (1.0f + erff(x * 0.70710678118654752f));
}

// async global->LDS direct copy, 16B per lane. LDS dest must be
// wave-uniform-base + lane*16 in lane order (ours is addr = tid*16).
#define GLOAD16(gp, lp) __builtin_amdgcn_global_load_lds( \
    (const __attribute__((address_space(1))) unsigned int*)(gp), \
    (__attribute__((address_space(3))) unsigned int*)(lp), 16, 0, 0)

// ---------------- weight convert + transpose to bf16 ----------------
__global__ __launch_bounds__(256) void transpose_f32_bf16(
    const float* __restrict__ src, unsigned short* __restrict__ dst,
    int R, int C, int Cpad, long srcLS, long dstLS, int rowOff)
{
    __shared__ float tile[32][33];
    int l  = blockIdx.z;
    int c0 = blockIdx.x * 32, r0 = blockIdx.y * 32;
    const float* s = src + (long)l * srcLS;
    unsigned short* d = dst + (long)l * dstLS;
    int tx = threadIdx.x, ty = threadIdx.y;
#pragma unroll
    for (int k = 0; k < 4; k++) {
        int r = r0 + ty + 8*k, c = c0 + tx;
        float v = (r < R && c < C) ? s[(long)r * C + c] : 0.0f;
        tile[ty + 8*k][tx] = v;
    }
    __syncthreads();
#pragma unroll
    for (int k = 0; k < 4; k++) {
        int c = c0 + ty + 8*k, r = r0 + tx;
        if (c < Cpad && r < R)
            d[(long)(rowOff + c) * R + r] = f2bf(tile[tx][ty + 8*k]);
    }
}

// ---------------- stack bq|bk|bv -> (L,1536) ----------------
__global__ __launch_bounds__(256) void stack_bias_kernel(
    const float* __restrict__ bq, const float* __restrict__ bk,
    const float* __restrict__ bv, float* __restrict__ bqkv)
{
    int idx = blockIdx.x * 256 + threadIdx.x;
    if (idx >= NLAYER * 1536) return;
    int l = idx / 1536, r = idx - l * 1536;
    float v;
    if (r < 512)       v = bq[l*512 + r];
    else if (r < 1024) v = bk[l*512 + r - 512];
    else               v = bv[l*512 + r - 1024];
    bqkv[idx] = v;
}

// ---------------- embedding ----------------
__global__ __launch_bounds__(256) void embed_kernel(
    const float* __restrict__ x, const float* __restrict__ conv_w,
    const float* __restrict__ conv_b, const float* __restrict__ cls_tok,
    const float* __restrict__ abs_pos, const float* __restrict__ file_emb,
    const float* __restrict__ rank_emb, const float* __restrict__ diag_emb,
    const float* __restrict__ adiag_emb, float* __restrict__ h)
{
    int b = blockIdx.y, sg = blockIdx.x, t = threadIdx.x;
    if (sg == 8) {
        for (int d = t; d < 512; d += 256)
            h[(long)b * SEQ * 512 + d] = cls_tok[d];
        return;
    }
    __shared__ float xs[112][8];
    for (int idx = t; idx < 112*8; idx += 256) {
        int c = idx >> 3, j = idx & 7;
        xs[c][j] = x[((long)b*112 + c)*64 + sg*8 + j];
    }
    __syncthreads();
    int d0 = t, d1 = t + 256;
    float acc0[8] = {}, acc1[8] = {};
    for (int c = 0; c < 112; c++) {
        float w0 = conv_w[c*512 + d0], w1 = conv_w[c*512 + d1];
#pragma unroll
        for (int j = 0; j < 8; j++) { acc0[j] += xs[c][j]*w0; acc1[j] += xs[c][j]*w1; }
    }
#pragma unroll
    for (int j = 0; j < 8; j++) {
        int sq = sg*8 + j, r = sq >> 3, f = sq & 7;
        long row = ((long)b * SEQ + 1 + sq) * 512;
        h[row + d0] = acc0[j] + conv_b[d0] + abs_pos[sq*512+d0] + file_emb[f*512+d0]
                    + rank_emb[r*512+d0] + diag_emb[(r+f)*512+d0] + adiag_emb[(r-f+7)*512+d0];
        h[row + d1] = acc1[j] + conv_b[d1] + abs_pos[sq*512+d1] + file_emb[f*512+d1]
                    + rank_emb[r*512+d1] + diag_emb[(r+f)*512+d1] + adiag_emb[(r-f+7)*512+d1];
    }
}

// ---------------- LayerNorm fp32 -> bf16 (wave per row) ----------------
__global__ __launch_bounds__(256) void ln_kernel(
    const float* __restrict__ hx, const float* __restrict__ g,
    const float* __restrict__ bb, unsigned short* __restrict__ o)
{
    int row  = blockIdx.x * 4 + (threadIdx.x >> 6);
    int lane = threadIdx.x & 63;
    const float4* xr = (const float4*)(hx + (long)row * 512);
    float4 v0 = xr[lane], v1 = xr[lane + 64];
    float s  = v0.x+v0.y+v0.z+v0.w + v1.x+v1.y+v1.z+v1.w;
    float s2 = v0.x*v0.x+v0.y*v0.y+v0.z*v0.z+v0.w*v0.w
             + v1.x*v1.x+v1.y*v1.y+v1.z*v1.z+v1.w*v1.w;
    for (int off = 32; off; off >>= 1) { s += __shfl_xor(s, off); s2 += __shfl_xor(s2, off); }
    float mean = s * (1.0f/512.0f);
    float var  = s2 * (1.0f/512.0f) - mean*mean;
    float rs   = rsqrtf(var + 1e-5f);
    const float4* gr = (const float4*)g; const float4* br = (const float4*)bb;
    float4 g0 = gr[lane], g1 = gr[lane+64], b0 = br[lane], b1 = br[lane+64];
    ushort4 o0, o1;
    o0.x = f2bf((v0.x-mean)*rs*g0.x + b0.x);
    o0.y = f2bf((v0.y-mean)*rs*g0.y + b0.y);
    o0.z = f2bf((v0.z-mean)*rs*g0.z + b0.z);
    o0.w = f2bf((v0.w-mean)*rs*g0.w + b0.w);
    o1.x = f2bf((v1.x-mean)*rs*g1.x + b1.x);
    o1.y = f2bf((v1.y-mean)*rs*g1.y + b1.y);
    o1.z = f2bf((v1.z-mean)*rs*g1.z + b1.z);
    o1.w = f2bf((v1.w-mean)*rs*g1.w + b1.w);
    ushort4* orow = (ushort4*)(o + (long)row * 512);
    orow[lane] = o0; orow[lane + 64] = o1;
}

// ---------------- MFMA GEMM, async-staged (m97 structure) ----------------
// tile 128x128, BK=32, 4 waves (32 rows x 128 cols each), 16x16x32 MFMA
// MODE 0: bias, bf16 out   MODE 1: bias + fp32 residual, fp32 out
// MODE 2: GLU pair -> bf16 gelu(u1)*u2, out (M,1920)
// MODE 3: policy masked store -> fp32 (B,4608)
template<int MODE>
__global__ __launch_bounds__(256) void gemm128(
    const unsigned short* __restrict__ A, const unsigned short* __restrict__ Bt,
    const float* __restrict__ bias, const float* __restrict__ res,
    void* __restrict__ out, int K, int ldo)
{
    __shared__ __attribute__((aligned(16))) unsigned short As[128*32];
    __shared__ __attribute__((aligned(16))) unsigned short Bs[128*32];
    int m0 = blockIdx.x * 128;
    int bn = blockIdx.y;
    int tid = threadIdx.x;
    int lane = tid & 63, w = tid >> 6;
    int quad = lane >> 4, col = lane & 15;

    int srow = tid >> 2;          // 0..63
    int sc8  = (tid & 3) * 8;     // k element offset (8 bf16 = 16B)

    int br0, br1;
    if (MODE == 2) {
        br0 = bn*64 + srow;                 // u1 rows
        br1 = 1920 + bn*64 + srow;          // u2 rows
    } else {
        br0 = bn*128 + srow;
        br1 = bn*128 + srow + 64;
    }
    const unsigned short* Arow0 = A + (long)(m0 + srow) * K + sc8;
    const unsigned short* Arow1 = A + (long)(m0 + srow + 64) * K + sc8;
    const unsigned short* Brow0 = Bt + (long)br0 * K + sc8;
    const unsigned short* Brow1 = Bt + (long)br1 * K + sc8;
    unsigned short* lAs0 = &As[srow*32 + sc8];          // byte addr = tid*16
    unsigned short* lAs1 = &As[(srow+64)*32 + sc8];
    unsigned short* lBs0 = &Bs[srow*32 + sc8];
    unsigned short* lBs1 = &Bs[(srow+64)*32 + sc8];

    f32x4 acc[2][8] = {};

    for (int k0 = 0; k0 < K; k0 += 32) {
        GLOAD16(Arow0 + k0, lAs0);
        GLOAD16(Arow1 + k0, lAs1);
        GLOAD16(Brow0 + k0, lBs0);
        GLOAD16(Brow1 + k0, lBs1);
        __syncthreads();           // drains vmcnt -> staging visible
        bf16x8 af[2], bfr[8];
#pragma unroll
        for (int i = 0; i < 2; i++)
            af[i] = *(const bf16x8*)(&As[(w*32 + i*16 + col)*32 + quad*8]);
#pragma unroll
        for (int t = 0; t < 8; t++)
            bfr[t] = *(const bf16x8*)(&Bs[(t*16 + col)*32 + quad*8]);
#pragma unroll
        for (int i = 0; i < 2; i++)
#pragma unroll
            for (int t = 0; t < 8; t++)
                acc[i][t] = __builtin_amdgcn_mfma_f32_16x16x32_bf16(af[i], bfr[t], acc[i][t], 0, 0, 0);
        __syncthreads();           // frag reads done before next overwrite
    }

    // ---- epilogue ----  C/D layout: col = lane&15, row = quad*4 + reg
    if (MODE == 2) {
        unsigned short* O = (unsigned short*)out;
        int gn0 = bn * 64;
#pragma unroll
        for (int i = 0; i < 2; i++)
#pragma unroll
        for (int t = 0; t < 4; t++) {
            int c = t*16 + col;
            float b1v = bias[gn0 + c];
            float b2v = bias[1920 + gn0 + c];
#pragma unroll
            for (int r = 0; r < 4; r++) {
                int m = m0 + w*32 + i*16 + quad*4 + r;
                float u1 = acc[i][t][r]   + b1v;
                float u2 = acc[i][t+4][r] + b2v;
                O[(long)m * DFFH + gn0 + c] = f2bf(gelu_exact(u1) * u2);
            }
        }
        return;
    }
    int n0 = bn * 128;
#pragma unroll
    for (int i = 0; i < 2; i++)
#pragma unroll
    for (int t = 0; t < 8; t++) {
        int cg = n0 + t*16 + col;
        float bv = (MODE == 3) ? (cg < 72 ? bias[cg] : 0.0f) : bias[cg];
#pragma unroll
        for (int r = 0; r < 4; r++) {
            int m = m0 + w*32 + i*16 + quad*4 + r;
            float v = acc[i][t][r] + bv;
            if (MODE == 0) {
                ((unsigned short*)out)[(long)m * ldo + cg] = f2bf(v);
            } else if (MODE == 1) {
                ((float*)out)[(long)m * ldo + cg] = res[(long)m * ldo + cg] + v;
            } else { // MODE 3 policy
                if (cg < 72) {
                    int b2 = m / 65, s = m - b2 * 65;
                    if (s > 0)
                        ((float*)out)[(long)b2 * 4608 + (s - 1) * 72 + cg] = v;
                }
            }
        }
    }
}

// ---------------- MFMA attention: one block per (head, batch) ----------------
// S = (Q/8) K^T (65x65 via 5x5 tiles of 16x16x32, K=64) ; softmax fp32 ;
// P (bf16, zero-padded to K=96) @ V via Vt (transposed V in LDS).
__global__ __launch_bounds__(256) void attn_mfma_kernel(
    const unsigned short* __restrict__ qkv,   // (M,1536) bf16: q|k|v
    const float* __restrict__ rel_bias,       // (13,15,15,8)
    unsigned short* __restrict__ ctx,         // (M,512) bf16
    int layer)
{
    constexpr int QS = 72;    // Qs/Ks stride: 144B rows -> 16B-aligned, ~2-way banks
    constexpr int VS = 104;   // Vt stride: 208B rows
    constexpr int SS = 68;    // Sf stride (fp32)
    constexpr int PS = 104;   // Pb stride
    __shared__ __attribute__((aligned(16))) unsigned short Qs[80*QS];
    __shared__ __attribute__((aligned(16))) unsigned short Ks[80*QS];
    __shared__ __attribute__((aligned(16))) unsigned short Vt[64*VS];
    __shared__ __attribute__((aligned(16))) float Sf[65*SS];
    __shared__ __attribute__((aligned(16))) unsigned short Pb[80*PS];
    __shared__ float bias_s[225];

    int h = blockIdx.x, b = blockIdx.y, t = threadIdx.x;
    int lane = t & 63, w = t >> 6;
    int quad = lane >> 4, col = lane & 15;

    for (int i = t; i < 225; i += 256)
        bias_s[i] = rel_bias[((long)layer*225 + i)*8 + h];

    // stage q (x0.125, exact), k, v^T
    for (int i = t; i < 65*8; i += 256) {
        int s = i >> 3, c8 = (i & 7) * 8;
        const unsigned short* row = qkv + ((long)(b*65+s))*1536 + h*64 + c8;
        int4 qv = *(const int4*)(row);
        int4 kv = *(const int4*)(row + 512);
        int4 vv = *(const int4*)(row + 1024);
        unsigned short qsc[8];
        const unsigned short* qp = (const unsigned short*)&qv;
#pragma unroll
        for (int j = 0; j < 8; j++) qsc[j] = f2bf(bf2f(qp[j]) * 0.125f);
        *(int4*)&Qs[s*QS + c8] = *(const int4*)qsc;
        *(int4*)&Ks[s*QS + c8] = kv;
        const unsigned short* vp = (const unsigned short*)&vv;
#pragma unroll
        for (int j = 0; j < 8; j++) Vt[(c8+j)*VS + s] = vp[j];
    }
    // zero Vt pad cols s=65..95 (avoid 0*NaN in PV)
    for (int i = t; i < 64*31; i += 256) {
        int d = i / 31, s = 65 + i % 31;
        Vt[d*VS + s] = 0;
    }
    __syncthreads();

    // QK^T : 25 tiles over 4 waves
    for (int tt = w; tt < 25; tt += 4) {
        int mi = tt / 5, nj = tt % 5;
        f32x4 acc = {};
        bf16x8 a0 = *(const bf16x8*)&Qs[(mi*16+col)*QS + quad*8];
        bf16x8 b0 = *(const bf16x8*)&Ks[(nj*16+col)*QS + quad*8];
        acc = __builtin_amdgcn_mfma_f32_16x16x32_bf16(a0, b0, acc, 0, 0, 0);
        bf16x8 a1 = *(const bf16x8*)&Qs[(mi*16+col)*QS + 32 + quad*8];
        bf16x8 b1 = *(const bf16x8*)&Ks[(nj*16+col)*QS + 32 + quad*8];
        acc = __builtin_amdgcn_mfma_f32_16x16x32_bf16(a1, b1, acc, 0, 0, 0);
#pragma unroll
        for (int r = 0; r < 4; r++) {
            int qi = mi*16 + quad*4 + r, kj = nj*16 + col;
            if (qi < 65 && kj < 65) {
                float v = acc[r];
                if (qi >= 1 && kj >= 1) {
                    int i2 = qi - 1, j2 = kj - 1;
                    int dr = (i2 >> 3) - (j2 >> 3) + 7;
                    int df = (i2 & 7) - (j2 & 7) + 7;
                    v += bias_s[dr*15 + df];
                }
                Sf[qi*SS + kj] = v;
            }
        }
    }
    __syncthreads();

    // softmax (wave per row), write bf16 P, zero pad cols 65..95
    for (int r = w; r < 65; r += 4) {
        float x0 = Sf[r*SS + lane];
        float x1 = (lane == 0) ? Sf[r*SS + 64] : -1e30f;
        float mx = fmaxf(x0, x1);
        for (int off = 32; off; off >>= 1) mx = fmaxf(mx, __shfl_xor(mx, off));
        float e0 = __expf(x0 - mx);
        float e1 = (lane == 0) ? __expf(x1 - mx) : 0.0f;
        float sm = e0 + e1;
        for (int off = 32; off; off >>= 1) sm += __shfl_xor(sm, off);
        float inv = 1.0f / sm;
        Pb[r*PS + lane] = f2bf(e0 * inv);
        if (lane == 0)  Pb[r*PS + 64] = f2bf(e1 * inv);
        if (lane >= 1 && lane <= 31) Pb[r*PS + 64 + lane] = 0;
    }
    __syncthreads();

    // ctx = P @ V : 20 tiles (5 row x 4 col) over 4 waves, K=96
    for (int tt = w; tt < 20; tt += 4) {
        int mi = tt >> 2, dj = tt & 3;
        f32x4 acc = {};
#pragma unroll
        for (int ks = 0; ks < 3; ks++) {
            bf16x8 a  = *(const bf16x8*)&Pb[(mi*16+col)*PS + ks*32 + quad*8];
            bf16x8 bb = *(const bf16x8*)&Vt[(dj*16+col)*VS + ks*32 + quad*8];
            acc = __builtin_amdgcn_mfma_f32_16x16x32_bf16(a, bb, acc, 0, 0, 0);
        }
#pragma unroll
        for (int r = 0; r < 4; r++) {
            int qi = mi*16 + quad*4 + r;
            if (qi < 65)
                ctx[((long)(b*65+qi))*512 + h*64 + dj*16 + col] = f2bf(acc[r]);
        }
    }
}

// ---------------- value head ----------------
__global__ __launch_bounds__(256) void value_head_kernel(
    const unsigned short* __restrict__ hn,
    const float* __restrict__ vw1, const float* __restrict__ vb1,
    const float* __restrict__ vw2, const float* __restrict__ vb2,
    const float* __restrict__ vw3, const float* __restrict__ vb3,
    float* __restrict__ outv)
{
    int b = blockIdx.x, t = threadIdx.x;
    __shared__ float cls[512], v1[256], v2[128];
    for (int d = t; d < 512; d += 256) cls[d] = bf2f(hn[(long)b * SEQ * 512 + d]);
    __syncthreads();
    {
        float a = vb1[t];
        for (int c = 0; c < 512; c++) a += cls[c] * vw1[c*256 + t];
        v1[t] = gelu_exact(a);
    }
    __syncthreads();
    if (t < 128) {
        float a = vb2[t];
        for (int c = 0; c < 256; c++) a += v1[c] * vw2[c*128 + t];
        v2[t] = gelu_exact(a);
    }
    __syncthreads();
    if (t < 3) {
        float a = vb3[t];
        for (int c = 0; c < 128; c++) a += v2[c] * vw3[c*3 + t];
        outv[b*3 + t] = a;
    }
}

// ---------------- host orchestration ----------------
extern "C" void kernel_launch(void* const* d_in, const int* in_sizes, int n_in,
                              void* d_out, int out_size, void* d_ws, size_t ws_size,
                              hipStream_t stream)
{
    (void)in_sizes; (void)n_in; (void)out_size; (void)ws_size;
    const float* x        = (const float*)d_in[0];
    const float* conv_w   = (const float*)d_in[1];
    const float* conv_b   = (const float*)d_in[2];
    const float* cls_tok  = (const float*)d_in[3];
    const float* abs_pos  = (const float*)d_in[4];
    const float* file_emb = (const float*)d_in[5];
    const float* rank_emb = (const float*)d_in[6];
    const float* diag_emb = (const float*)d_in[7];
    const float* adiag    = (const float*)d_in[8];
    const float* ln1_g    = (const float*)d_in[9];
    const float* ln1_b    = (const float*)d_in[10];
    const float* wq       = (const float*)d_in[11];
    const float* bq       = (const float*)d_in[12];
    const float* wk       = (const float*)d_in[13];
    const float* bk       = (const float*)d_in[14];
    const float* wv       = (const float*)d_in[15];
    const float* bv       = (const float*)d_in[16];
    const float* wo       = (const float*)d_in[17];
    const float* bo       = (const float*)d_in[18];
    const float* rel_bias = (const float*)d_in[19];
    const float* ln2_g    = (const float*)d_in[20];
    const float* ln2_b    = (const float*)d_in[21];
    const float* w_ff1    = (const float*)d_in[22];
    const float* b_ff1    = (const float*)d_in[23];
    const float* w_ff2    = (const float*)d_in[24];
    const float* b_ff2    = (const float*)d_in[25];
    const float* out_g    = (const float*)d_in[26];
    const float* out_b    = (const float*)d_in[27];
    const float* vw1      = (const float*)d_in[28];
    const float* vb1      = (const float*)d_in[29];
    const float* vw2      = (const float*)d_in[30];
    const float* vb2      = (const float*)d_in[31];
    const float* vw3      = (const float*)d_in[32];
    const float* vb3      = (const float*)d_in[33];
    const float* pw       = (const float*)d_in[34];
    const float* pb       = (const float*)d_in[35];

    char* p = (char*)d_ws;
    auto alloc = [&](size_t bytes) { void* r = (void*)p; p += (bytes + 255) & ~(size_t)255; return r; };
    unsigned short* qkvT = (unsigned short*)alloc((size_t)NLAYER*1536*512*2);
    unsigned short* woT  = (unsigned short*)alloc((size_t)NLAYER*512*512*2);
    unsigned short* w1T  = (unsigned short*)alloc((size_t)NLAYER*3840*512*2);
    unsigned short* w2T  = (unsigned short*)alloc((size_t)NLAYER*512*1920*2);
    unsigned short* pwT  = (unsigned short*)alloc((size_t)128*512*2);
    float*          bqkv = (float*)alloc((size_t)NLAYER*1536*4);
    float*          h    = (float*)alloc((size_t)MROWS*512*4);
    unsigned short* nbf  = (unsigned short*)alloc((size_t)MROWS*512*2);
    unsigned short* qkvb = (unsigned short*)alloc((size_t)MROWS*1536*2);
    unsigned short* ctxb = (unsigned short*)alloc((size_t)MROWS*512*2);
    unsigned short* gbuf = (unsigned short*)alloc((size_t)MROWS*1920*2);

    dim3 tb(32, 8);
    transpose_f32_bf16<<<dim3(16,16,NLAYER), tb, 0, stream>>>(wq, qkvT, 512, 512, 512, 512L*512, 1536L*512, 0);
    transpose_f32_bf16<<<dim3(16,16,NLAYER), tb, 0, stream>>>(wk, qkvT, 512, 512, 512, 512L*512, 1536L*512, 512);
    transpose_f32_bf16<<<dim3(16,16,NLAYER), tb, 0, stream>>>(wv, qkvT, 512, 512, 512, 512L*512, 1536L*512, 1024);
    transpose_f32_bf16<<<dim3(16,16,NLAYER), tb, 0, stream>>>(wo, woT, 512, 512, 512, 512L*512, 512L*512, 0);
    transpose_f32_bf16<<<dim3(120,16,NLAYER), tb, 0, stream>>>(w_ff1, w1T, 512, 3840, 3840, 512L*3840, 3840L*512, 0);
    transpose_f32_bf16<<<dim3(16,60,NLAYER), tb, 0, stream>>>(w_ff2, w2T, 1920, 512, 512, 1920L*512, 512L*1920, 0);
    transpose_f32_bf16<<<dim3(4,16,1), tb, 0, stream>>>(pw, pwT, 512, 72, 128, 0, 0, 0);
    stack_bias_kernel<<<(NLAYER*1536 + 255)/256, 256, 0, stream>>>(bq, bk, bv, bqkv);

    embed_kernel<<<dim3(9, BATCH), 256, 0, stream>>>(x, conv_w, conv_b, cls_tok, abs_pos,
                                                     file_emb, rank_emb, diag_emb, adiag, h);

    for (int l = 0; l < NLAYER; l++) {
        ln_kernel<<<MROWS/4, 256, 0, stream>>>(h, ln1_g + l*512, ln1_b + l*512, nbf);
        gemm128<0><<<dim3(65,12), 256, 0, stream>>>(nbf, qkvT + (size_t)l*1536*512,
                                                    bqkv + l*1536, nullptr, qkvb, 512, 1536);
        attn_mfma_kernel<<<dim3(NHEAD, BATCH), 256, 0, stream>>>(qkvb, rel_bias, ctxb, l);
        gemm128<1><<<dim3(65,4), 256, 0, stream>>>(ctxb, woT + (size_t)l*512*512,
                                                   bo + l*512, h, h, 512, 512);
        ln_kernel<<<MROWS/4, 256, 0, stream>>>(h, ln2_g + l*512, ln2_b + l*512, nbf);
        gemm128<2><<<dim3(65,30), 256, 0, stream>>>(nbf, w1T + (size_t)l*3840*512,
                                                    b_ff1 + l*3840, nullptr, gbuf, 512, 0);
        gemm128<1><<<dim3(65,4), 256, 0, stream>>>(gbuf, w2T + (size_t)l*512*1920,
                                                   b_ff2 + l*512, h, h, 1920, 512);
    }

    ln_kernel<<<MROWS/4, 256, 0, stream>>>(h, out_g, out_b, nbf);
    gemm128<3><<<dim3(65,1), 256, 0, stream>>>(nbf, pwT, pb, nullptr, (float*)d_out, 512, 0);
    value_head_kernel<<<BATCH, 256, 0, stream>>>(nbf, vw1, vb1, vw2, vb2, vw3, vb3,
                                                 (float*)d_out + (size_t)BATCH*4608);
}

// Round 3
// 3160.724 us; speedup vs baseline: 1.1324x; 1.0354x over previous
//
#include <hip/hip_runtime.h>
#include <stdint.h>

// ---------------- problem constants ----------------
#define NLAYER 13
#define DMODEL 512
#define SEQ    65
#define BATCH  128
#define MROWS  (BATCH*SEQ)   // 8320 = 65 * 128 exactly
#define NHEAD  8
#define DFFH   1920          // half of 2*DFF

typedef __bf16 bf16x8 __attribute__((ext_vector_type(8)));
typedef float  f32x4  __attribute__((ext_vector_type(4)));

__device__ __forceinline__ float bf2f(unsigned short u) {
    union { unsigned int i; float f; } c; c.i = ((unsigned int)u) << 16; return c.f;
}
__device__ __forceinline__ unsigned short f2bf(float f) {
    union { float f; unsigned int i; } c; c.f = f;
    unsigned int u = c.i;
    u += 0x7fffu + ((u >> 16) & 1u);   // RNE
    return (unsigned short)(u >> 16);
}
__device__ __forceinline__ float gelu_exact(float x) {
    return 0.5f * x * (1.0f + erff(x * 0.70710678118654752f));
}

// async global->LDS direct copy, 16B per lane. LDS dest must be
// wave-uniform base + lane*16 in lane order (ours is addr = tid*16).
#define GLOAD16(gp, lp) __builtin_amdgcn_global_load_lds( \
    (const __attribute__((address_space(1))) unsigned int*)(gp), \
    (__attribute__((address_space(3))) unsigned int*)(lp), 16, 0, 0)

// ---------------- weight convert + transpose to bf16 ----------------
__global__ __launch_bounds__(256) void transpose_f32_bf16(
    const float* __restrict__ src, unsigned short* __restrict__ dst,
    int R, int C, int Cpad, long srcLS, long dstLS, int rowOff)
{
    __shared__ float tile[32][33];
    int l  = blockIdx.z;
    int c0 = blockIdx.x * 32, r0 = blockIdx.y * 32;
    const float* s = src + (long)l * srcLS;
    unsigned short* d = dst + (long)l * dstLS;
    int tx = threadIdx.x, ty = threadIdx.y;
#pragma unroll
    for (int k = 0; k < 4; k++) {
        int r = r0 + ty + 8*k, c = c0 + tx;
        float v = (r < R && c < C) ? s[(long)r * C + c] : 0.0f;
        tile[ty + 8*k][tx] = v;
    }
    __syncthreads();
#pragma unroll
    for (int k = 0; k < 4; k++) {
        int c = c0 + ty + 8*k, r = r0 + tx;
        if (c < Cpad && r < R)
            d[(long)(rowOff + c) * R + r] = f2bf(tile[tx][ty + 8*k]);
    }
}

// ---------------- stack bq|bk|bv -> (L,1536) ----------------
__global__ __launch_bounds__(256) void stack_bias_kernel(
    const float* __restrict__ bq, const float* __restrict__ bk,
    const float* __restrict__ bv, float* __restrict__ bqkv)
{
    int idx = blockIdx.x * 256 + threadIdx.x;
    if (idx >= NLAYER * 1536) return;
    int l = idx / 1536, r = idx - l * 1536;
    float v;
    if (r < 512)       v = bq[l*512 + r];
    else if (r < 1024) v = bk[l*512 + r - 512];
    else               v = bv[l*512 + r - 1024];
    bqkv[idx] = v;
}

// ---------------- embedding ----------------
__global__ __launch_bounds__(256) void embed_kernel(
    const float* __restrict__ x, const float* __restrict__ conv_w,
    const float* __restrict__ conv_b, const float* __restrict__ cls_tok,
    const float* __restrict__ abs_pos, const float* __restrict__ file_emb,
    const float* __restrict__ rank_emb, const float* __restrict__ diag_emb,
    const float* __restrict__ adiag_emb, float* __restrict__ h)
{
    int b = blockIdx.y, sg = blockIdx.x, t = threadIdx.x;
    if (sg == 8) {
        for (int d = t; d < 512; d += 256)
            h[(long)b * SEQ * 512 + d] = cls_tok[d];
        return;
    }
    __shared__ float xs[112][8];
    for (int idx = t; idx < 112*8; idx += 256) {
        int c = idx >> 3, j = idx & 7;
        xs[c][j] = x[((long)b*112 + c)*64 + sg*8 + j];
    }
    __syncthreads();
    int d0 = t, d1 = t + 256;
    float acc0[8] = {}, acc1[8] = {};
    for (int c = 0; c < 112; c++) {
        float w0 = conv_w[c*512 + d0], w1 = conv_w[c*512 + d1];
#pragma unroll
        for (int j = 0; j < 8; j++) { acc0[j] += xs[c][j]*w0; acc1[j] += xs[c][j]*w1; }
    }
#pragma unroll
    for (int j = 0; j < 8; j++) {
        int sq = sg*8 + j, r = sq >> 3, f = sq & 7;
        long row = ((long)b * SEQ + 1 + sq) * 512;
        h[row + d0] = acc0[j] + conv_b[d0] + abs_pos[sq*512+d0] + file_emb[f*512+d0]
                    + rank_emb[r*512+d0] + diag_emb[(r+f)*512+d0] + adiag_emb[(r-f+7)*512+d0];
        h[row + d1] = acc1[j] + conv_b[d1] + abs_pos[sq*512+d1] + file_emb[f*512+d1]
                    + rank_emb[r*512+d1] + diag_emb[(r+f)*512+d1] + adiag_emb[(r-f+7)*512+d1];
    }
}

// ---------------- LayerNorm fp32 -> bf16 (wave per row) ----------------
__global__ __launch_bounds__(256) void ln_kernel(
    const float* __restrict__ hx, const float* __restrict__ g,
    const float* __restrict__ bb, unsigned short* __restrict__ o)
{
    int row  = blockIdx.x * 4 + (threadIdx.x >> 6);
    int lane = threadIdx.x & 63;
    const float4* xr = (const float4*)(hx + (long)row * 512);
    float4 v0 = xr[lane], v1 = xr[lane + 64];
    float s  = v0.x+v0.y+v0.z+v0.w + v1.x+v1.y+v1.z+v1.w;
    float s2 = v0.x*v0.x+v0.y*v0.y+v0.z*v0.z+v0.w*v0.w
             + v1.x*v1.x+v1.y*v1.y+v1.z*v1.z+v1.w*v1.w;
    for (int off = 32; off; off >>= 1) { s += __shfl_xor(s, off); s2 += __shfl_xor(s2, off); }
    float mean = s * (1.0f/512.0f);
    float var  = s2 * (1.0f/512.0f) - mean*mean;
    float rs   = rsqrtf(var + 1e-5f);
    const float4* gr = (const float4*)g; const float4* br = (const float4*)bb;
    float4 g0 = gr[lane], g1 = gr[lane+64], b0 = br[lane], b1 = br[lane+64];
    ushort4 o0, o1;
    o0.x = f2bf((v0.x-mean)*rs*g0.x + b0.x);
    o0.y = f2bf((v0.y-mean)*rs*g0.y + b0.y);
    o0.z = f2bf((v0.z-mean)*rs*g0.z + b0.z);
    o0.w = f2bf((v0.w-mean)*rs*g0.w + b0.w);
    o1.x = f2bf((v1.x-mean)*rs*g1.x + b1.x);
    o1.y = f2bf((v1.y-mean)*rs*g1.y + b1.y);
    o1.z = f2bf((v1.z-mean)*rs*g1.z + b1.z);
    o1.w = f2bf((v1.w-mean)*rs*g1.w + b1.w);
    ushort4* orow = (ushort4*)(o + (long)row * 512);
    orow[lane] = o0; orow[lane + 64] = o1;
}

// ---------------- MFMA GEMM, async-staged (m97 structure) ----------------
// tile 128x128, BK=32, 4 waves (32 rows x 128 cols each), 16x16x32 MFMA
// GRID: x = n-tile (fastest), y = m-tile  -> m-major launch order so the
// concurrent block window shares the full B panel (L2-resident) and a small
// A window; kills the A re-fetch seen in R2 (FETCH 110MB -> ~25MB predicted).
// MODE 0: bias, bf16 out   MODE 1: bias + fp32 residual, fp32 out
// MODE 2: GLU pair -> bf16 gelu(u1)*u2, out (M,1920)
// MODE 3: policy masked store -> fp32 (B,4608)
template<int MODE>
__global__ __launch_bounds__(256) void gemm128(
    const unsigned short* __restrict__ A, const unsigned short* __restrict__ Bt,
    const float* __restrict__ bias, const float* __restrict__ res,
    void* __restrict__ out, int K, int ldo)
{
    __shared__ __attribute__((aligned(16))) unsigned short As[128*32];
    __shared__ __attribute__((aligned(16))) unsigned short Bs[128*32];
    int m0 = blockIdx.y * 128;     // m-tile from y (slow axis)
    int bn = blockIdx.x;           // n-tile from x (fast axis)
    int tid = threadIdx.x;
    int lane = tid & 63, w = tid >> 6;
    int quad = lane >> 4, col = lane & 15;

    int srow = tid >> 2;          // 0..63
    int sc8  = (tid & 3) * 8;     // k element offset (8 bf16 = 16B)

    int br0, br1;
    if (MODE == 2) {
        br0 = bn*64 + srow;                 // u1 rows
        br1 = 1920 + bn*64 + srow;          // u2 rows
    } else {
        br0 = bn*128 + srow;
        br1 = bn*128 + srow + 64;
    }
    const unsigned short* Arow0 = A + (long)(m0 + srow) * K + sc8;
    const unsigned short* Arow1 = A + (long)(m0 + srow + 64) * K + sc8;
    const unsigned short* Brow0 = Bt + (long)br0 * K + sc8;
    const unsigned short* Brow1 = Bt + (long)br1 * K + sc8;
    unsigned short* lAs0 = &As[srow*32 + sc8];          // byte addr = tid*16
    unsigned short* lAs1 = &As[(srow+64)*32 + sc8];
    unsigned short* lBs0 = &Bs[srow*32 + sc8];
    unsigned short* lBs1 = &Bs[(srow+64)*32 + sc8];

    f32x4 acc[2][8] = {};

    for (int k0 = 0; k0 < K; k0 += 32) {
        GLOAD16(Arow0 + k0, lAs0);
        GLOAD16(Arow1 + k0, lAs1);
        GLOAD16(Brow0 + k0, lBs0);
        GLOAD16(Brow1 + k0, lBs1);
        __syncthreads();           // drains vmcnt -> staging visible
        bf16x8 af[2], bfr[8];
#pragma unroll
        for (int i = 0; i < 2; i++)
            af[i] = *(const bf16x8*)(&As[(w*32 + i*16 + col)*32 + quad*8]);
#pragma unroll
        for (int t = 0; t < 8; t++)
            bfr[t] = *(const bf16x8*)(&Bs[(t*16 + col)*32 + quad*8]);
#pragma unroll
        for (int i = 0; i < 2; i++)
#pragma unroll
            for (int t = 0; t < 8; t++)
                acc[i][t] = __builtin_amdgcn_mfma_f32_16x16x32_bf16(af[i], bfr[t], acc[i][t], 0, 0, 0);
        __syncthreads();           // frag reads done before next overwrite
    }

    // ---- epilogue ----  C/D layout: col = lane&15, row = quad*4 + reg
    if (MODE == 2) {
        unsigned short* O = (unsigned short*)out;
        int gn0 = bn * 64;
#pragma unroll
        for (int i = 0; i < 2; i++)
#pragma unroll
        for (int t = 0; t < 4; t++) {
            int c = t*16 + col;
            float b1v = bias[gn0 + c];
            float b2v = bias[1920 + gn0 + c];
#pragma unroll
            for (int r = 0; r < 4; r++) {
                int m = m0 + w*32 + i*16 + quad*4 + r;
                float u1 = acc[i][t][r]   + b1v;
                float u2 = acc[i][t+4][r] + b2v;
                O[(long)m * DFFH + gn0 + c] = f2bf(gelu_exact(u1) * u2);
            }
        }
        return;
    }
    int n0 = bn * 128;
#pragma unroll
    for (int i = 0; i < 2; i++)
#pragma unroll
    for (int t = 0; t < 8; t++) {
        int cg = n0 + t*16 + col;
        float bv = (MODE == 3) ? (cg < 72 ? bias[cg] : 0.0f) : bias[cg];
#pragma unroll
        for (int r = 0; r < 4; r++) {
            int m = m0 + w*32 + i*16 + quad*4 + r;
            float v = acc[i][t][r] + bv;
            if (MODE == 0) {
                ((unsigned short*)out)[(long)m * ldo + cg] = f2bf(v);
            } else if (MODE == 1) {
                ((float*)out)[(long)m * ldo + cg] = res[(long)m * ldo + cg] + v;
            } else { // MODE 3 policy
                if (cg < 72) {
                    int b2 = m / 65, s = m - b2 * 65;
                    if (s > 0)
                        ((float*)out)[(long)b2 * 4608 + (s - 1) * 72 + cg] = v;
                }
            }
        }
    }
}

// ---------------- MFMA attention: one block per (head, batch) ----------------
__global__ __launch_bounds__(256) void attn_mfma_kernel(
    const unsigned short* __restrict__ qkv,   // (M,1536) bf16: q|k|v
    const float* __restrict__ rel_bias,       // (13,15,15,8)
    unsigned short* __restrict__ ctx,         // (M,512) bf16
    int layer)
{
    constexpr int QS = 72;
    constexpr int VS = 104;
    constexpr int SS = 68;
    constexpr int PS = 104;
    __shared__ __attribute__((aligned(16))) unsigned short Qs[80*QS];
    __shared__ __attribute__((aligned(16))) unsigned short Ks[80*QS];
    __shared__ __attribute__((aligned(16))) unsigned short Vt[64*VS];
    __shared__ __attribute__((aligned(16))) float Sf[65*SS];
    __shared__ __attribute__((aligned(16))) unsigned short Pb[80*PS];
    __shared__ float bias_s[225];

    int h = blockIdx.x, b = blockIdx.y, t = threadIdx.x;
    int lane = t & 63, w = t >> 6;
    int quad = lane >> 4, col = lane & 15;

    for (int i = t; i < 225; i += 256)
        bias_s[i] = rel_bias[((long)layer*225 + i)*8 + h];

    for (int i = t; i < 65*8; i += 256) {
        int s = i >> 3, c8 = (i & 7) * 8;
        const unsigned short* row = qkv + ((long)(b*65+s))*1536 + h*64 + c8;
        int4 qv = *(const int4*)(row);
        int4 kv = *(const int4*)(row + 512);
        int4 vv = *(const int4*)(row + 1024);
        unsigned short qsc[8];
        const unsigned short* qp = (const unsigned short*)&qv;
#pragma unroll
        for (int j = 0; j < 8; j++) qsc[j] = f2bf(bf2f(qp[j]) * 0.125f);
        *(int4*)&Qs[s*QS + c8] = *(const int4*)qsc;
        *(int4*)&Ks[s*QS + c8] = kv;
        const unsigned short* vp = (const unsigned short*)&vv;
#pragma unroll
        for (int j = 0; j < 8; j++) Vt[(c8+j)*VS + s] = vp[j];
    }
    for (int i = t; i < 64*31; i += 256) {
        int d = i / 31, s = 65 + i % 31;
        Vt[d*VS + s] = 0;
    }
    __syncthreads();

    for (int tt = w; tt < 25; tt += 4) {
        int mi = tt / 5, nj = tt % 5;
        f32x4 acc = {};
        bf16x8 a0 = *(const bf16x8*)&Qs[(mi*16+col)*QS + quad*8];
        bf16x8 b0 = *(const bf16x8*)&Ks[(nj*16+col)*QS + quad*8];
        acc = __builtin_amdgcn_mfma_f32_16x16x32_bf16(a0, b0, acc, 0, 0, 0);
        bf16x8 a1 = *(const bf16x8*)&Qs[(mi*16+col)*QS + 32 + quad*8];
        bf16x8 b1 = *(const bf16x8*)&Ks[(nj*16+col)*QS + 32 + quad*8];
        acc = __builtin_amdgcn_mfma_f32_16x16x32_bf16(a1, b1, acc, 0, 0, 0);
#pragma unroll
        for (int r = 0; r < 4; r++) {
            int qi = mi*16 + quad*4 + r, kj = nj*16 + col;
            if (qi < 65 && kj < 65) {
                float v = acc[r];
                if (qi >= 1 && kj >= 1) {
                    int i2 = qi - 1, j2 = kj - 1;
                    int dr = (i2 >> 3) - (j2 >> 3) + 7;
                    int df = (i2 & 7) - (j2 & 7) + 7;
                    v += bias_s[dr*15 + df];
                }
                Sf[qi*SS + kj] = v;
            }
        }
    }
    __syncthreads();

    for (int r = w; r < 65; r += 4) {
        float x0 = Sf[r*SS + lane];
        float x1 = (lane == 0) ? Sf[r*SS + 64] : -1e30f;
        float mx = fmaxf(x0, x1);
        for (int off = 32; off; off >>= 1) mx = fmaxf(mx, __shfl_xor(mx, off));
        float e0 = __expf(x0 - mx);
        float e1 = (lane == 0) ? __expf(x1 - mx) : 0.0f;
        float sm = e0 + e1;
        for (int off = 32; off; off >>= 1) sm += __shfl_xor(sm, off);
        float inv = 1.0f / sm;
        Pb[r*PS + lane] = f2bf(e0 * inv);
        if (lane == 0)  Pb[r*PS + 64] = f2bf(e1 * inv);
        if (lane >= 1 && lane <= 31) Pb[r*PS + 64 + lane] = 0;
    }
    __syncthreads();

    for (int tt = w; tt < 20; tt += 4) {
        int mi = tt >> 2, dj = tt & 3;
        f32x4 acc = {};
#pragma unroll
        for (int ks = 0; ks < 3; ks++) {
            bf16x8 a  = *(const bf16x8*)&Pb[(mi*16+col)*PS + ks*32 + quad*8];
            bf16x8 bb = *(const bf16x8*)&Vt[(dj*16+col)*VS + ks*32 + quad*8];
            acc = __builtin_amdgcn_mfma_f32_16x16x32_bf16(a, bb, acc, 0, 0, 0);
        }
#pragma unroll
        for (int r = 0; r < 4; r++) {
            int qi = mi*16 + quad*4 + r;
            if (qi < 65)
                ctx[((long)(b*65+qi))*512 + h*64 + dj*16 + col] = f2bf(acc[r]);
        }
    }
}

// ---------------- value head ----------------
__global__ __launch_bounds__(256) void value_head_kernel(
    const unsigned short* __restrict__ hn,
    const float* __restrict__ vw1, const float* __restrict__ vb1,
    const float* __restrict__ vw2, const float* __restrict__ vb2,
    const float* __restrict__ vw3, const float* __restrict__ vb3,
    float* __restrict__ outv)
{
    int b = blockIdx.x, t = threadIdx.x;
    __shared__ float cls[512], v1[256], v2[128];
    for (int d = t; d < 512; d += 256) cls[d] = bf2f(hn[(long)b * SEQ * 512 + d]);
    __syncthreads();
    {
        float a = vb1[t];
        for (int c = 0; c < 512; c++) a += cls[c] * vw1[c*256 + t];
        v1[t] = gelu_exact(a);
    }
    __syncthreads();
    if (t < 128) {
        float a = vb2[t];
        for (int c = 0; c < 256; c++) a += v1[c] * vw2[c*128 + t];
        v2[t] = gelu_exact(a);
    }
    __syncthreads();
    if (t < 3) {
        float a = vb3[t];
        for (int c = 0; c < 128; c++) a += v2[c] * vw3[c*3 + t];
        outv[b*3 + t] = a;
    }
}

// ---------------- host orchestration ----------------
extern "C" void kernel_launch(void* const* d_in, const int* in_sizes, int n_in,
                              void* d_out, int out_size, void* d_ws, size_t ws_size,
                              hipStream_t stream)
{
    (void)in_sizes; (void)n_in; (void)out_size; (void)ws_size;
    const float* x        = (const float*)d_in[0];
    const float* conv_w   = (const float*)d_in[1];
    const float* conv_b   = (const float*)d_in[2];
    const float* cls_tok  = (const float*)d_in[3];
    const float* abs_pos  = (const float*)d_in[4];
    const float* file_emb = (const float*)d_in[5];
    const float* rank_emb = (const float*)d_in[6];
    const float* diag_emb = (const float*)d_in[7];
    const float* adiag    = (const float*)d_in[8];
    const float* ln1_g    = (const float*)d_in[9];
    const float* ln1_b    = (const float*)d_in[10];
    const float* wq       = (const float*)d_in[11];
    const float* bq       = (const float*)d_in[12];
    const float* wk       = (const float*)d_in[13];
    const float* bk       = (const float*)d_in[14];
    const float* wv       = (const float*)d_in[15];
    const float* bv       = (const float*)d_in[16];
    const float* wo       = (const float*)d_in[17];
    const float* bo       = (const float*)d_in[18];
    const float* rel_bias = (const float*)d_in[19];
    const float* ln2_g    = (const float*)d_in[20];
    const float* ln2_b    = (const float*)d_in[21];
    const float* w_ff1    = (const float*)d_in[22];
    const float* b_ff1    = (const float*)d_in[23];
    const float* w_ff2    = (const float*)d_in[24];
    const float* b_ff2    = (const float*)d_in[25];
    const float* out_g    = (const float*)d_in[26];
    const float* out_b    = (const float*)d_in[27];
    const float* vw1      = (const float*)d_in[28];
    const float* vb1      = (const float*)d_in[29];
    const float* vw2      = (const float*)d_in[30];
    const float* vb2      = (const float*)d_in[31];
    const float* vw3      = (const float*)d_in[32];
    const float* vb3      = (const float*)d_in[33];
    const float* pw       = (const float*)d_in[34];
    const float* pb       = (const float*)d_in[35];

    char* p = (char*)d_ws;
    auto alloc = [&](size_t bytes) { void* r = (void*)p; p += (bytes + 255) & ~(size_t)255; return r; };
    unsigned short* qkvT = (unsigned short*)alloc((size_t)NLAYER*1536*512*2);
    unsigned short* woT  = (unsigned short*)alloc((size_t)NLAYER*512*512*2);
    unsigned short* w1T  = (unsigned short*)alloc((size_t)NLAYER*3840*512*2);
    unsigned short* w2T  = (unsigned short*)alloc((size_t)NLAYER*512*1920*2);
    unsigned short* pwT  = (unsigned short*)alloc((size_t)128*512*2);
    float*          bqkv = (float*)alloc((size_t)NLAYER*1536*4);
    float*          h    = (float*)alloc((size_t)MROWS*512*4);
    unsigned short* nbf  = (unsigned short*)alloc((size_t)MROWS*512*2);
    unsigned short* qkvb = (unsigned short*)alloc((size_t)MROWS*1536*2);
    unsigned short* ctxb = (unsigned short*)alloc((size_t)MROWS*512*2);
    unsigned short* gbuf = (unsigned short*)alloc((size_t)MROWS*1920*2);

    dim3 tb(32, 8);
    transpose_f32_bf16<<<dim3(16,16,NLAYER), tb, 0, stream>>>(wq, qkvT, 512, 512, 512, 512L*512, 1536L*512, 0);
    transpose_f32_bf16<<<dim3(16,16,NLAYER), tb, 0, stream>>>(wk, qkvT, 512, 512, 512, 512L*512, 1536L*512, 512);
    transpose_f32_bf16<<<dim3(16,16,NLAYER), tb, 0, stream>>>(wv, qkvT, 512, 512, 512, 512L*512, 1536L*512, 1024);
    transpose_f32_bf16<<<dim3(16,16,NLAYER), tb, 0, stream>>>(wo, woT, 512, 512, 512, 512L*512, 512L*512, 0);
    transpose_f32_bf16<<<dim3(120,16,NLAYER), tb, 0, stream>>>(w_ff1, w1T, 512, 3840, 3840, 512L*3840, 3840L*512, 0);
    transpose_f32_bf16<<<dim3(16,60,NLAYER), tb, 0, stream>>>(w_ff2, w2T, 1920, 512, 512, 1920L*512, 512L*1920, 0);
    transpose_f32_bf16<<<dim3(4,16,1), tb, 0, stream>>>(pw, pwT, 512, 72, 128, 0, 0, 0);
    stack_bias_kernel<<<(NLAYER*1536 + 255)/256, 256, 0, stream>>>(bq, bk, bv, bqkv);

    embed_kernel<<<dim3(9, BATCH), 256, 0, stream>>>(x, conv_w, conv_b, cls_tok, abs_pos,
                                                     file_emb, rank_emb, diag_emb, adiag, h);

    for (int l = 0; l < NLAYER; l++) {
        ln_kernel<<<MROWS/4, 256, 0, stream>>>(h, ln1_g + l*512, ln1_b + l*512, nbf);
        gemm128<0><<<dim3(12,65), 256, 0, stream>>>(nbf, qkvT + (size_t)l*1536*512,
                                                    bqkv + l*1536, nullptr, qkvb, 512, 1536);
        attn_mfma_kernel<<<dim3(NHEAD, BATCH), 256, 0, stream>>>(qkvb, rel_bias, ctxb, l);
        gemm128<1><<<dim3(4,65), 256, 0, stream>>>(ctxb, woT + (size_t)l*512*512,
                                                   bo + l*512, h, h, 512, 512);
        ln_kernel<<<MROWS/4, 256, 0, stream>>>(h, ln2_g + l*512, ln2_b + l*512, nbf);
        gemm128<2><<<dim3(30,65), 256, 0, stream>>>(nbf, w1T + (size_t)l*3840*512,
                                                    b_ff1 + l*3840, nullptr, gbuf, 512, 0);
        gemm128<1><<<dim3(4,65), 256, 0, stream>>>(gbuf, w2T + (size_t)l*512*1920,
                                                   b_ff2 + l*512, h, h, 1920, 512);
    }

    ln_kernel<<<MROWS/4, 256, 0, stream>>>(h, out_g, out_b, nbf);
    gemm128<3><<<dim3(1,65), 256, 0, stream>>>(nbf, pwT, pb, nullptr, (float*)d_out, 512, 0);
    value_head_kernel<<<BATCH, 256, 0, stream>>>(nbf, vw1, vb1, vw2, vb2, vw3, vb3,
                                                 (float*)d_out + (size_t)BATCH*4608);
}

// Round 5
// 2873.538 us; speedup vs baseline: 1.2456x; 1.0999x over previous
//
#include <hip/hip_runtime.h>
#include <stdint.h>

// ---------------- problem constants ----------------
#define NLAYER 13
#define DMODEL 512
#define SEQ    65
#define BATCH  128
#define MROWS  (BATCH*SEQ)   // 8320 = 65 * 128 exactly
#define NHEAD  8
#define DFFH   1920          // half of 2*DFF
#define MTILES 65            // MROWS / 128
#define MBAND  9             // ceil(65/8) m-tiles per XCD slice

typedef __bf16 bf16x8 __attribute__((ext_vector_type(8)));
typedef float  f32x4  __attribute__((ext_vector_type(4)));

__device__ __forceinline__ float bf2f(unsigned short u) {
    union { unsigned int i; float f; } c; c.i = ((unsigned int)u) << 16; return c.f;
}
__device__ __forceinline__ unsigned short f2bf(float f) {
    union { float f; unsigned int i; } c; c.f = f;
    unsigned int u = c.i;
    u += 0x7fffu + ((u >> 16) & 1u);   // RNE
    return (unsigned short)(u >> 16);
}
__device__ __forceinline__ float gelu_exact(float x) {
    return 0.5f * x * (1.0f + erff(x * 0.70710678118654752f));
}

// ---------------- weight convert + transpose to bf16 ----------------
__global__ __launch_bounds__(256) void transpose_f32_bf16(
    const float* __restrict__ src, unsigned short* __restrict__ dst,
    int R, int C, int Cpad, long srcLS, long dstLS, int rowOff)
{
    __shared__ float tile[32][33];
    int l  = blockIdx.z;
    int c0 = blockIdx.x * 32, r0 = blockIdx.y * 32;
    const float* s = src + (long)l * srcLS;
    unsigned short* d = dst + (long)l * dstLS;
    int tx = threadIdx.x, ty = threadIdx.y;
#pragma unroll
    for (int k = 0; k < 4; k++) {
        int r = r0 + ty + 8*k, c = c0 + tx;
        float v = (r < R && c < C) ? s[(long)r * C + c] : 0.0f;
        tile[ty + 8*k][tx] = v;
    }
    __syncthreads();
#pragma unroll
    for (int k = 0; k < 4; k++) {
        int c = c0 + ty + 8*k, r = r0 + tx;
        if (c < Cpad && r < R)
            d[(long)(rowOff + c) * R + r] = f2bf(tile[tx][ty + 8*k]);
    }
}

// ---------------- stack bq|bk|bv -> (L,1536) ----------------
__global__ __launch_bounds__(256) void stack_bias_kernel(
    const float* __restrict__ bq, const float* __restrict__ bk,
    const float* __restrict__ bv, float* __restrict__ bqkv)
{
    int idx = blockIdx.x * 256 + threadIdx.x;
    if (idx >= NLAYER * 1536) return;
    int l = idx / 1536, r = idx - l * 1536;
    float v;
    if (r < 512)       v = bq[l*512 + r];
    else if (r < 1024) v = bk[l*512 + r - 512];
    else               v = bv[l*512 + r - 1024];
    bqkv[idx] = v;
}

// ---------------- embedding ----------------
__global__ __launch_bounds__(256) void embed_kernel(
    const float* __restrict__ x, const float* __restrict__ conv_w,
    const float* __restrict__ conv_b, const float* __restrict__ cls_tok,
    const float* __restrict__ abs_pos, const float* __restrict__ file_emb,
    const float* __restrict__ rank_emb, const float* __restrict__ diag_emb,
    const float* __restrict__ adiag_emb, float* __restrict__ h)
{
    int b = blockIdx.y, sg = blockIdx.x, t = threadIdx.x;
    if (sg == 8) {
        for (int d = t; d < 512; d += 256)
            h[(long)b * SEQ * 512 + d] = cls_tok[d];
        return;
    }
    __shared__ float xs[112][8];
    for (int idx = t; idx < 112*8; idx += 256) {
        int c = idx >> 3, j = idx & 7;
        xs[c][j] = x[((long)b*112 + c)*64 + sg*8 + j];
    }
    __syncthreads();
    int d0 = t, d1 = t + 256;
    float acc0[8] = {}, acc1[8] = {};
    for (int c = 0; c < 112; c++) {
        float w0 = conv_w[c*512 + d0], w1 = conv_w[c*512 + d1];
#pragma unroll
        for (int j = 0; j < 8; j++) { acc0[j] += xs[c][j]*w0; acc1[j] += xs[c][j]*w1; }
    }
#pragma unroll
    for (int j = 0; j < 8; j++) {
        int sq = sg*8 + j, r = sq >> 3, f = sq & 7;
        long row = ((long)b * SEQ + 1 + sq) * 512;
        h[row + d0] = acc0[j] + conv_b[d0] + abs_pos[sq*512+d0] + file_emb[f*512+d0]
                    + rank_emb[r*512+d0] + diag_emb[(r+f)*512+d0] + adiag_emb[(r-f+7)*512+d0];
        h[row + d1] = acc1[j] + conv_b[d1] + abs_pos[sq*512+d1] + file_emb[f*512+d1]
                    + rank_emb[r*512+d1] + diag_emb[(r+f)*512+d1] + adiag_emb[(r-f+7)*512+d1];
    }
}

// ---------------- LayerNorm fp32 -> bf16 (wave per row) ----------------
__global__ __launch_bounds__(256) void ln_kernel(
    const float* __restrict__ hx, const float* __restrict__ g,
    const float* __restrict__ bb, unsigned short* __restrict__ o)
{
    int row  = blockIdx.x * 4 + (threadIdx.x >> 6);
    int lane = threadIdx.x & 63;
    const float4* xr = (const float4*)(hx + (long)row * 512);
    float4 v0 = xr[lane], v1 = xr[lane + 64];
    float s  = v0.x+v0.y+v0.z+v0.w + v1.x+v1.y+v1.z+v1.w;
    float s2 = v0.x*v0.x+v0.y*v0.y+v0.z*v0.z+v0.w*v0.w
             + v1.x*v1.x+v1.y*v1.y+v1.z*v1.z+v1.w*v1.w;
    for (int off = 32; off; off >>= 1) { s += __shfl_xor(s, off); s2 += __shfl_xor(s2, off); }
    float mean = s * (1.0f/512.0f);
    float var  = s2 * (1.0f/512.0f) - mean*mean;
    float rs   = rsqrtf(var + 1e-5f);
    const float4* gr = (const float4*)g; const float4* br = (const float4*)bb;
    float4 g0 = gr[lane], g1 = gr[lane+64], b0 = br[lane], b1 = br[lane+64];
    ushort4 o0, o1;
    o0.x = f2bf((v0.x-mean)*rs*g0.x + b0.x);
    o0.y = f2bf((v0.y-mean)*rs*g0.y + b0.y);
    o0.z = f2bf((v0.z-mean)*rs*g0.z + b0.z);
    o0.w = f2bf((v0.w-mean)*rs*g0.w + b0.w);
    o1.x = f2bf((v1.x-mean)*rs*g1.x + b1.x);
    o1.y = f2bf((v1.y-mean)*rs*g1.y + b1.y);
    o1.z = f2bf((v1.z-mean)*rs*g1.z + b1.z);
    o1.w = f2bf((v1.w-mean)*rs*g1.w + b1.w);
    ushort4* orow = (ushort4*)(o + (long)row * 512);
    orow[lane] = o0; orow[lane + 64] = o1;
}

// ---------------- MFMA GEMM: XCD-swizzled + register-prefetch pipeline ------
// tile 128x128, BK=32, 4 waves (32 rows x 128 cols each), 16x16x32 MFMA.
// 1D grid of 72*nT blocks: xcd = id&7 owns a contiguous band of 9 m-tiles,
// n fastest inside the band -> each A row lives in one XCD's L2; B panel
// stays L3-resident.
// K-loop = R1-proven register-prefetch shape (replay-safe): next tile's
// global loads issue into VGPRs before the MFMA phase (latency hidden),
// ds_write at top of next iteration. NOTE: global_load_lds double-buffering
// raced under graph replay (R4) — do not reintroduce without a fix.
// MODE 0: bias, bf16 out   MODE 1: bias + fp32 residual, fp32 out
// MODE 2: GLU pair -> bf16 gelu(u1)*u2, out (M,1920)
// MODE 3: policy masked store -> fp32 (B,4608)
template<int MODE>
__global__ __launch_bounds__(256) void gemm128(
    const unsigned short* __restrict__ A, const unsigned short* __restrict__ Bt,
    const float* __restrict__ bias, const float* __restrict__ res,
    void* __restrict__ out, int K, int ldo, int nT)
{
    __shared__ __attribute__((aligned(16))) unsigned short As[128*32];
    __shared__ __attribute__((aligned(16))) unsigned short Bs[128*32];
    int id = blockIdx.x;
    int xcd = id & 7, jj = id >> 3;
    int bn  = jj % nT;
    int mt  = xcd * MBAND + jj / nT;
    if (mt >= MTILES) return;
    int m0 = mt * 128;
    int tid = threadIdx.x;
    int lane = tid & 63, w = tid >> 6;
    int quad = lane >> 4, col = lane & 15;

    int srow = tid >> 2;          // 0..63
    int sc8  = (tid & 3) * 8;     // k element offset (8 bf16 = 16B)

    int br0, br1;
    if (MODE == 2) {
        br0 = bn*64 + srow;                 // u1 rows
        br1 = 1920 + bn*64 + srow;          // u2 rows
    } else {
        br0 = bn*128 + srow;
        br1 = bn*128 + srow + 64;
    }
    const unsigned short* Arow0 = A + (long)(m0 + srow) * K + sc8;
    const unsigned short* Arow1 = A + (long)(m0 + srow + 64) * K + sc8;
    const unsigned short* Brow0 = Bt + (long)br0 * K + sc8;
    const unsigned short* Brow1 = Bt + (long)br1 * K + sc8;

    f32x4 acc[2][8] = {};

    int4 ca0 = *(const int4*)(Arow0);
    int4 ca1 = *(const int4*)(Arow1);
    int4 cb0 = *(const int4*)(Brow0);
    int4 cb1 = *(const int4*)(Brow1);

    for (int k0 = 0; k0 < K; k0 += 32) {
        __syncthreads();   // prior iteration's frag reads done
        *(int4*)(&As[srow*32 + sc8])        = ca0;
        *(int4*)(&As[(srow+64)*32 + sc8])   = ca1;
        *(int4*)(&Bs[srow*32 + sc8])        = cb0;
        *(int4*)(&Bs[(srow+64)*32 + sc8])   = cb1;
        __syncthreads();
        int kn = k0 + 32;
        if (kn < K) {   // prefetch next tile into VGPRs while computing
            ca0 = *(const int4*)(Arow0 + kn);
            ca1 = *(const int4*)(Arow1 + kn);
            cb0 = *(const int4*)(Brow0 + kn);
            cb1 = *(const int4*)(Brow1 + kn);
        }
        bf16x8 af[2], bfr[8];
#pragma unroll
        for (int i = 0; i < 2; i++)
            af[i] = *(const bf16x8*)(&As[(w*32 + i*16 + col)*32 + quad*8]);
#pragma unroll
        for (int t = 0; t < 8; t++)
            bfr[t] = *(const bf16x8*)(&Bs[(t*16 + col)*32 + quad*8]);
#pragma unroll
        for (int i = 0; i < 2; i++)
#pragma unroll
            for (int t = 0; t < 8; t++)
                acc[i][t] = __builtin_amdgcn_mfma_f32_16x16x32_bf16(af[i], bfr[t], acc[i][t], 0, 0, 0);
    }

    // ---- epilogue ----  C/D layout: col = lane&15, row = quad*4 + reg
    if (MODE == 2) {
        unsigned short* O = (unsigned short*)out;
        int gn0 = bn * 64;
#pragma unroll
        for (int i = 0; i < 2; i++)
#pragma unroll
        for (int t = 0; t < 4; t++) {
            int c = t*16 + col;
            float b1v = bias[gn0 + c];
            float b2v = bias[1920 + gn0 + c];
#pragma unroll
            for (int r = 0; r < 4; r++) {
                int m = m0 + w*32 + i*16 + quad*4 + r;
                float u1 = acc[i][t][r]   + b1v;
                float u2 = acc[i][t+4][r] + b2v;
                O[(long)m * DFFH + gn0 + c] = f2bf(gelu_exact(u1) * u2);
            }
        }
        return;
    }
    int n0 = bn * 128;
#pragma unroll
    for (int i = 0; i < 2; i++)
#pragma unroll
    for (int t = 0; t < 8; t++) {
        int cg = n0 + t*16 + col;
        float bv = (MODE == 3) ? (cg < 72 ? bias[cg] : 0.0f) : bias[cg];
#pragma unroll
        for (int r = 0; r < 4; r++) {
            int m = m0 + w*32 + i*16 + quad*4 + r;
            float v = acc[i][t][r] + bv;
            if (MODE == 0) {
                ((unsigned short*)out)[(long)m * ldo + cg] = f2bf(v);
            } else if (MODE == 1) {
                ((float*)out)[(long)m * ldo + cg] = res[(long)m * ldo + cg] + v;
            } else { // MODE 3 policy
                if (cg < 72) {
                    int b2 = m / 65, s = m - b2 * 65;
                    if (s > 0)
                        ((float*)out)[(long)b2 * 4608 + (s - 1) * 72 + cg] = v;
                }
            }
        }
    }
}

// ---------------- MFMA attention: one block per (head, batch) ----------------
__global__ __launch_bounds__(256) void attn_mfma_kernel(
    const unsigned short* __restrict__ qkv,   // (M,1536) bf16: q|k|v
    const float* __restrict__ rel_bias,       // (13,15,15,8)
    unsigned short* __restrict__ ctx,         // (M,512) bf16
    int layer)
{
    constexpr int QS = 72;
    constexpr int VS = 104;
    constexpr int SS = 68;
    constexpr int PS = 104;
    __shared__ __attribute__((aligned(16))) unsigned short Qs[80*QS];
    __shared__ __attribute__((aligned(16))) unsigned short Ks[80*QS];
    __shared__ __attribute__((aligned(16))) unsigned short Vt[64*VS];
    __shared__ __attribute__((aligned(16))) float Sf[65*SS];
    __shared__ __attribute__((aligned(16))) unsigned short Pb[80*PS];
    __shared__ float bias_s[225];

    int h = blockIdx.x, b = blockIdx.y, t = threadIdx.x;
    int lane = t & 63, w = t >> 6;
    int quad = lane >> 4, col = lane & 15;

    for (int i = t; i < 225; i += 256)
        bias_s[i] = rel_bias[((long)layer*225 + i)*8 + h];

    for (int i = t; i < 65*8; i += 256) {
        int s = i >> 3, c8 = (i & 7) * 8;
        const unsigned short* row = qkv + ((long)(b*65+s))*1536 + h*64 + c8;
        int4 qv = *(const int4*)(row);
        int4 kv = *(const int4*)(row + 512);
        int4 vv = *(const int4*)(row + 1024);
        unsigned short qsc[8];
        const unsigned short* qp = (const unsigned short*)&qv;
#pragma unroll
        for (int j = 0; j < 8; j++) qsc[j] = f2bf(bf2f(qp[j]) * 0.125f);
        *(int4*)&Qs[s*QS + c8] = *(const int4*)qsc;
        *(int4*)&Ks[s*QS + c8] = kv;
        const unsigned short* vp = (const unsigned short*)&vv;
#pragma unroll
        for (int j = 0; j < 8; j++) Vt[(c8+j)*VS + s] = vp[j];
    }
    for (int i = t; i < 64*31; i += 256) {
        int d = i / 31, s = 65 + i % 31;
        Vt[d*VS + s] = 0;
    }
    __syncthreads();

    for (int tt = w; tt < 25; tt += 4) {
        int mi = tt / 5, nj = tt % 5;
        f32x4 acc = {};
        bf16x8 a0 = *(const bf16x8*)&Qs[(mi*16+col)*QS + quad*8];
        bf16x8 b0 = *(const bf16x8*)&Ks[(nj*16+col)*QS + quad*8];
        acc = __builtin_amdgcn_mfma_f32_16x16x32_bf16(a0, b0, acc, 0, 0, 0);
        bf16x8 a1 = *(const bf16x8*)&Qs[(mi*16+col)*QS + 32 + quad*8];
        bf16x8 b1 = *(const bf16x8*)&Ks[(nj*16+col)*QS + 32 + quad*8];
        acc = __builtin_amdgcn_mfma_f32_16x16x32_bf16(a1, b1, acc, 0, 0, 0);
#pragma unroll
        for (int r = 0; r < 4; r++) {
            int qi = mi*16 + quad*4 + r, kj = nj*16 + col;
            if (qi < 65 && kj < 65) {
                float v = acc[r];
                if (qi >= 1 && kj >= 1) {
                    int i2 = qi - 1, j2 = kj - 1;
                    int dr = (i2 >> 3) - (j2 >> 3) + 7;
                    int df = (i2 & 7) - (j2 & 7) + 7;
                    v += bias_s[dr*15 + df];
                }
                Sf[qi*SS + kj] = v;
            }
        }
    }
    __syncthreads();

    for (int r = w; r < 65; r += 4) {
        float x0 = Sf[r*SS + lane];
        float x1 = (lane == 0) ? Sf[r*SS + 64] : -1e30f;
        float mx = fmaxf(x0, x1);
        for (int off = 32; off; off >>= 1) mx = fmaxf(mx, __shfl_xor(mx, off));
        float e0 = __expf(x0 - mx);
        float e1 = (lane == 0) ? __expf(x1 - mx) : 0.0f;
        float sm = e0 + e1;
        for (int off = 32; off; off >>= 1) sm += __shfl_xor(sm, off);
        float inv = 1.0f / sm;
        Pb[r*PS + lane] = f2bf(e0 * inv);
        if (lane == 0)  Pb[r*PS + 64] = f2bf(e1 * inv);
        if (lane >= 1 && lane <= 31) Pb[r*PS + 64 + lane] = 0;
    }
    __syncthreads();

    for (int tt = w; tt < 20; tt += 4) {
        int mi = tt >> 2, dj = tt & 3;
        f32x4 acc = {};
#pragma unroll
        for (int ks = 0; ks < 3; ks++) {
            bf16x8 a  = *(const bf16x8*)&Pb[(mi*16+col)*PS + ks*32 + quad*8];
            bf16x8 bb = *(const bf16x8*)&Vt[(dj*16+col)*VS + ks*32 + quad*8];
            acc = __builtin_amdgcn_mfma_f32_16x16x32_bf16(a, bb, acc, 0, 0, 0);
        }
#pragma unroll
        for (int r = 0; r < 4; r++) {
            int qi = mi*16 + quad*4 + r;
            if (qi < 65)
                ctx[((long)(b*65+qi))*512 + h*64 + dj*16 + col] = f2bf(acc[r]);
        }
    }
}

// ---------------- value head ----------------
__global__ __launch_bounds__(256) void value_head_kernel(
    const unsigned short* __restrict__ hn,
    const float* __restrict__ vw1, const float* __restrict__ vb1,
    const float* __restrict__ vw2, const float* __restrict__ vb2,
    const float* __restrict__ vw3, const float* __restrict__ vb3,
    float* __restrict__ outv)
{
    int b = blockIdx.x, t = threadIdx.x;
    __shared__ float cls[512], v1[256], v2[128];
    for (int d = t; d < 512; d += 256) cls[d] = bf2f(hn[(long)b * SEQ * 512 + d]);
    __syncthreads();
    {
        float a = vb1[t];
        for (int c = 0; c < 512; c++) a += cls[c] * vw1[c*256 + t];
        v1[t] = gelu_exact(a);
    }
    __syncthreads();
    if (t < 128) {
        float a = vb2[t];
        for (int c = 0; c < 256; c++) a += v1[c] * vw2[c*128 + t];
        v2[t] = gelu_exact(a);
    }
    __syncthreads();
    if (t < 3) {
        float a = vb3[t];
        for (int c = 0; c < 128; c++) a += v2[c] * vw3[c*3 + t];
        outv[b*3 + t] = a;
    }
}

// ---------------- host orchestration ----------------
extern "C" void kernel_launch(void* const* d_in, const int* in_sizes, int n_in,
                              void* d_out, int out_size, void* d_ws, size_t ws_size,
                              hipStream_t stream)
{
    (void)in_sizes; (void)n_in; (void)out_size; (void)ws_size;
    const float* x        = (const float*)d_in[0];
    const float* conv_w   = (const float*)d_in[1];
    const float* conv_b   = (const float*)d_in[2];
    const float* cls_tok  = (const float*)d_in[3];
    const float* abs_pos  = (const float*)d_in[4];
    const float* file_emb = (const float*)d_in[5];
    const float* rank_emb = (const float*)d_in[6];
    const float* diag_emb = (const float*)d_in[7];
    const float* adiag    = (const float*)d_in[8];
    const float* ln1_g    = (const float*)d_in[9];
    const float* ln1_b    = (const float*)d_in[10];
    const float* wq       = (const float*)d_in[11];
    const float* bq       = (const float*)d_in[12];
    const float* wk       = (const float*)d_in[13];
    const float* bk       = (const float*)d_in[14];
    const float* wv       = (const float*)d_in[15];
    const float* bv       = (const float*)d_in[16];
    const float* wo       = (const float*)d_in[17];
    const float* bo       = (const float*)d_in[18];
    const float* rel_bias = (const float*)d_in[19];
    const float* ln2_g    = (const float*)d_in[20];
    const float* ln2_b    = (const float*)d_in[21];
    const float* w_ff1    = (const float*)d_in[22];
    const float* b_ff1    = (const float*)d_in[23];
    const float* w_ff2    = (const float*)d_in[24];
    const float* b_ff2    = (const float*)d_in[25];
    const float* out_g    = (const float*)d_in[26];
    const float* out_b    = (const float*)d_in[27];
    const float* vw1      = (const float*)d_in[28];
    const float* vb1      = (const float*)d_in[29];
    const float* vw2      = (const float*)d_in[30];
    const float* vb2      = (const float*)d_in[31];
    const float* vw3      = (const float*)d_in[32];
    const float* vb3      = (const float*)d_in[33];
    const float* pw       = (const float*)d_in[34];
    const float* pb       = (const float*)d_in[35];

    char* p = (char*)d_ws;
    auto alloc = [&](size_t bytes) { void* r = (void*)p; p += (bytes + 255) & ~(size_t)255; return r; };
    unsigned short* qkvT = (unsigned short*)alloc((size_t)NLAYER*1536*512*2);
    unsigned short* woT  = (unsigned short*)alloc((size_t)NLAYER*512*512*2);
    unsigned short* w1T  = (unsigned short*)alloc((size_t)NLAYER*3840*512*2);
    unsigned short* w2T  = (unsigned short*)alloc((size_t)NLAYER*512*1920*2);
    unsigned short* pwT  = (unsigned short*)alloc((size_t)128*512*2);
    float*          bqkv = (float*)alloc((size_t)NLAYER*1536*4);
    float*          h    = (float*)alloc((size_t)MROWS*512*4);
    unsigned short* nbf  = (unsigned short*)alloc((size_t)MROWS*512*2);
    unsigned short* qkvb = (unsigned short*)alloc((size_t)MROWS*1536*2);
    unsigned short* ctxb = (unsigned short*)alloc((size_t)MROWS*512*2);
    unsigned short* gbuf = (unsigned short*)alloc((size_t)MROWS*1920*2);

    dim3 tb(32, 8);
    transpose_f32_bf16<<<dim3(16,16,NLAYER), tb, 0, stream>>>(wq, qkvT, 512, 512, 512, 512L*512, 1536L*512, 0);
    transpose_f32_bf16<<<dim3(16,16,NLAYER), tb, 0, stream>>>(wk, qkvT, 512, 512, 512, 512L*512, 1536L*512, 512);
    transpose_f32_bf16<<<dim3(16,16,NLAYER), tb, 0, stream>>>(wv, qkvT, 512, 512, 512, 512L*512, 1536L*512, 1024);
    transpose_f32_bf16<<<dim3(16,16,NLAYER), tb, 0, stream>>>(wo, woT, 512, 512, 512, 512L*512, 512L*512, 0);
    transpose_f32_bf16<<<dim3(120,16,NLAYER), tb, 0, stream>>>(w_ff1, w1T, 512, 3840, 3840, 512L*3840, 3840L*512, 0);
    transpose_f32_bf16<<<dim3(16,60,NLAYER), tb, 0, stream>>>(w_ff2, w2T, 1920, 512, 512, 1920L*512, 512L*1920, 0);
    transpose_f32_bf16<<<dim3(4,16,1), tb, 0, stream>>>(pw, pwT, 512, 72, 128, 0, 0, 0);
    stack_bias_kernel<<<(NLAYER*1536 + 255)/256, 256, 0, stream>>>(bq, bk, bv, bqkv);

    embed_kernel<<<dim3(9, BATCH), 256, 0, stream>>>(x, conv_w, conv_b, cls_tok, abs_pos,
                                                     file_emb, rank_emb, diag_emb, adiag, h);

    for (int l = 0; l < NLAYER; l++) {
        ln_kernel<<<MROWS/4, 256, 0, stream>>>(h, ln1_g + l*512, ln1_b + l*512, nbf);
        gemm128<0><<<72*12, 256, 0, stream>>>(nbf, qkvT + (size_t)l*1536*512,
                                              bqkv + l*1536, nullptr, qkvb, 512, 1536, 12);
        attn_mfma_kernel<<<dim3(NHEAD, BATCH), 256, 0, stream>>>(qkvb, rel_bias, ctxb, l);
        gemm128<1><<<72*4, 256, 0, stream>>>(ctxb, woT + (size_t)l*512*512,
                                             bo + l*512, h, h, 512, 512, 4);
        ln_kernel<<<MROWS/4, 256, 0, stream>>>(h, ln2_g + l*512, ln2_b + l*512, nbf);
        gemm128<2><<<72*30, 256, 0, stream>>>(nbf, w1T + (size_t)l*3840*512,
                                              b_ff1 + l*3840, nullptr, gbuf, 512, 0, 30);
        gemm128<1><<<72*4, 256, 0, stream>>>(gbuf, w2T + (size_t)l*512*1920,
                                             b_ff2 + l*512, h, h, 1920, 512, 4);
    }

    ln_kernel<<<MROWS/4, 256, 0, stream>>>(h, out_g, out_b, nbf);
    gemm128<3><<<72*1, 256, 0, stream>>>(nbf, pwT, pb, nullptr, (float*)d_out, 512, 0, 1);
    value_head_kernel<<<BATCH, 256, 0, stream>>>(nbf, vw1, vb1, vw2, vb2, vw3, vb3,
                                                 (float*)d_out + (size_t)BATCH*4608);
}